// Round 1
// baseline (4032.006 us; speedup 1.0000x reference)
//
#include <hip/hip_runtime.h>
#include <hip/hip_bf16.h>
#include <cstddef>

#define D_MODEL 384
#define D_INNER 768
#define D_STATE 16
#define DT_RANK 24
#define K_CONV  4
#define BATCH   8
#define SEQ     2048
#define BL      (BATCH * SEQ)     // 16384 rows

// ---------------------------------------------------------------------------
// LayerNorm over last dim (384). One block per row, 384 threads.
// ---------------------------------------------------------------------------
__global__ __launch_bounds__(384) void ln_kernel(
    const float* __restrict__ in, const float* __restrict__ w,
    const float* __restrict__ b, float* __restrict__ out)
{
    int row = blockIdx.x;
    int tid = threadIdx.x;
    float v = in[(size_t)row * D_MODEL + tid];
    float s = v, sq = v * v;
    #pragma unroll
    for (int o = 32; o; o >>= 1) {
        s  += __shfl_down(s, o);
        sq += __shfl_down(sq, o);
    }
    __shared__ float ss[6], ssq[6];
    __shared__ float mb[2];
    int wid = tid >> 6;
    if ((tid & 63) == 0) { ss[wid] = s; ssq[wid] = sq; }
    __syncthreads();
    if (tid == 0) {
        float S = 0.f, Q = 0.f;
        #pragma unroll
        for (int k = 0; k < 6; k++) { S += ss[k]; Q += ssq[k]; }
        float mu  = S * (1.0f / D_MODEL);
        float var = Q * (1.0f / D_MODEL) - mu * mu;
        mb[0] = mu;
        mb[1] = rsqrtf(var + 1e-5f);
    }
    __syncthreads();
    out[(size_t)row * D_MODEL + tid] = (v - mb[0]) * mb[1] * w[tid] + b[tid];
}

// ---------------------------------------------------------------------------
// Generic C = A (MxK) * W^T (W is NxK) [+ resid], all row-major f32.
// 64x64x16 tiles, 256 threads, 4x4 per-thread microtile.
// resid/C may alias (same element read-then-written by same thread) -> no
// __restrict__ on those two.
// ---------------------------------------------------------------------------
__global__ __launch_bounds__(256) void gemm_atb(
    const float* __restrict__ A, const float* __restrict__ W,
    const float* resid, float* C, int M, int N, int K)
{
    __shared__ float As[16][68];
    __shared__ float Ws[16][68];
    int bm = blockIdx.x, bn = blockIdx.y;
    int tid = threadIdx.x;
    int tx = tid & 15, ty = tid >> 4;
    int lrow  = tid >> 2;          // 0..63
    int lcol4 = (tid & 3) * 4;     // 0,4,8,12

    const float* Ablk = A + (size_t)(bm * 64) * K;
    const float* Wblk = W + (size_t)(bn * 64) * K;

    float acc[4][4] = {};
    for (int k0 = 0; k0 < K; k0 += 16) {
        float4 av = *(const float4*)(Ablk + (size_t)lrow * K + k0 + lcol4);
        float4 wv = *(const float4*)(Wblk + (size_t)lrow * K + k0 + lcol4);
        As[lcol4 + 0][lrow] = av.x; As[lcol4 + 1][lrow] = av.y;
        As[lcol4 + 2][lrow] = av.z; As[lcol4 + 3][lrow] = av.w;
        Ws[lcol4 + 0][lrow] = wv.x; Ws[lcol4 + 1][lrow] = wv.y;
        Ws[lcol4 + 2][lrow] = wv.z; Ws[lcol4 + 3][lrow] = wv.w;
        __syncthreads();
        #pragma unroll
        for (int kk = 0; kk < 16; kk++) {
            float a[4], bfr[4];
            #pragma unroll
            for (int i = 0; i < 4; i++) a[i]   = As[kk][ty * 4 + i];
            #pragma unroll
            for (int j = 0; j < 4; j++) bfr[j] = Ws[kk][tx * 4 + j];
            #pragma unroll
            for (int i = 0; i < 4; i++)
                #pragma unroll
                for (int j = 0; j < 4; j++)
                    acc[i][j] = fmaf(a[i], bfr[j], acc[i][j]);
        }
        __syncthreads();
    }
    int r0 = bm * 64 + ty * 4;
    int c0 = bn * 64 + tx * 4;
    #pragma unroll
    for (int i = 0; i < 4; i++) {
        #pragma unroll
        for (int j = 0; j < 4; j++) {
            size_t idx = (size_t)(r0 + i) * N + c0 + j;
            float v = acc[i][j];
            if (resid) v += resid[idx];
            C[idx] = v;
        }
    }
}

// ---------------------------------------------------------------------------
// Causal depthwise conv (k=4) + bias + SiLU. dir=0: looks back; dir=1:
// looks forward with reversed kernel (equivalent to flip-conv-flip).
// Input: xs half of xz (cols 0..767 of 1536-wide rows).
// ---------------------------------------------------------------------------
__global__ __launch_bounds__(256) void conv_silu_kernel(
    const float* __restrict__ xz, const float* __restrict__ cw,
    const float* __restrict__ cb, float* __restrict__ xsc, int dir)
{
    int idx = blockIdx.x * 256 + threadIdx.x;   // BL * 768
    int c   = idx % D_INNER;
    int row = idx / D_INNER;     // b*SEQ + l
    int l   = row % SEQ;
    int b0  = row - l;
    float acc = cb[c];
    if (dir == 0) {
        #pragma unroll
        for (int k = 0; k < 4; k++) {
            int ls = l - 3 + k;
            if (ls >= 0)
                acc = fmaf(xz[(size_t)(b0 + ls) * 1536 + c], cw[c * 4 + k], acc);
        }
    } else {
        #pragma unroll
        for (int j = 0; j < 4; j++) {
            int ls = l + j;
            if (ls < SEQ)
                acc = fmaf(xz[(size_t)(b0 + ls) * 1536 + c], cw[c * 4 + 3 - j], acc);
        }
    }
    float sg = 1.0f / (1.0f + __expf(-acc));
    xsc[idx] = acc * sg;
}

// ---------------------------------------------------------------------------
// Per-row: x_dbl = xs @ x_proj^T (56 outs), then dt = softplus(dt_raw @ dt_w^T
// + dt_b) (768 outs), plus emit B (16) and C (16). One block per row, 256 thr.
// ---------------------------------------------------------------------------
__global__ __launch_bounds__(256) void xproj_dt_kernel(
    const float* __restrict__ xsc, const float* __restrict__ xproj,
    const float* __restrict__ dtw, const float* __restrict__ dtbias,
    float* __restrict__ dt_out, float* __restrict__ Bc, float* __restrict__ Cc)
{
    __shared__ float xs[D_INNER];
    __shared__ float xd[DT_RANK + 2 * D_STATE];
    int row = blockIdx.x;
    int tid = threadIdx.x;
    const float* xr = xsc + (size_t)row * D_INNER;
    #pragma unroll
    for (int j = 0; j < 3; j++) xs[tid + j * 256] = xr[tid + j * 256];
    __syncthreads();

    int o = tid >> 2, sub = tid & 3;
    if (o < 56) {
        float p = 0.f;
        const float* wr  = xproj + o * D_INNER + sub * 192;
        const float* xrr = xs + sub * 192;
        for (int k = 0; k < 192; k++) p = fmaf(xrr[k], wr[k], p);
        p += __shfl_xor(p, 1);
        p += __shfl_xor(p, 2);
        if (sub == 0) xd[o] = p;
    }
    __syncthreads();

    #pragma unroll
    for (int j = 0; j < 3; j++) {
        int d = tid + j * 256;
        float acc = dtbias[d];
        #pragma unroll
        for (int r = 0; r < DT_RANK; r++)
            acc = fmaf(xd[r], dtw[d * DT_RANK + r], acc);
        float sp = acc > 20.f ? acc : __logf(1.f + __expf(acc));
        dt_out[(size_t)row * D_INNER + d] = sp;
    }
    if (tid < D_STATE)
        Bc[(size_t)row * D_STATE + tid] = xd[DT_RANK + tid];
    else if (tid < 2 * D_STATE)
        Cc[(size_t)row * D_STATE + tid - D_STATE] = xd[DT_RANK + D_STATE + tid - D_STATE];
}

// ---------------------------------------------------------------------------
// Sequential selective scan over L. One thread per (b,d) chain, 16 states in
// registers. Also fuses D-skip and SiLU(z) gating. y may alias dt (each
// element is read before being overwritten by the same thread).
// ---------------------------------------------------------------------------
__global__ __launch_bounds__(256) void scan_kernel(
    const float* dt, const float* __restrict__ xsc,
    const float* __restrict__ xz, const float* __restrict__ Bc,
    const float* __restrict__ Cc, const float* __restrict__ A_log,
    const float* __restrict__ Dp, float* y, int dir)
{
    int g = blockIdx.x % 3, b = blockIdx.x / 3;
    int d = g * 256 + threadIdx.x;
    float A[D_STATE];
    #pragma unroll
    for (int n = 0; n < D_STATE; n++) A[n] = -__expf(A_log[d * D_STATE + n]);
    float Dd = Dp[d];
    float h[D_STATE] = {};
    size_t brow = (size_t)b * SEQ;
    for (int p = 0; p < SEQ; p++) {
        int l = dir ? (SEQ - 1 - p) : p;
        size_t row = brow + l;
        float dtv = dt[row * D_INNER + d];
        float xv  = xsc[row * D_INNER + d];
        float zv  = xz[row * 1536 + D_INNER + d];
        float dtx = dtv * xv;
        float yv = 0.f;
        #pragma unroll
        for (int n = 0; n < D_STATE; n++) {
            float Bn = Bc[row * D_STATE + n];
            float Cn = Cc[row * D_STATE + n];
            h[n] = fmaf(__expf(dtv * A[n]), h[n], dtx * Bn);
            yv = fmaf(h[n], Cn, yv);
        }
        yv = fmaf(xv, Dd, yv);
        float sg = 1.f / (1.f + __expf(-zv));
        yv *= zv * sg;
        y[row * D_INNER + d] = yv;
    }
}

// ---------------------------------------------------------------------------
extern "C" void kernel_launch(void* const* d_in, const int* in_sizes, int n_in,
                              void* d_out, int out_size, void* d_ws, size_t ws_size,
                              hipStream_t stream)
{
    const float* x       = (const float*)d_in[0];
    const float* norm_w  = (const float*)d_in[1];
    const float* norm_b  = (const float*)d_in[2];
    const float* in_proj = (const float*)d_in[3];
    const float* conv_w  = (const float*)d_in[4];
    const float* conv_b  = (const float*)d_in[5];
    const float* x_proj  = (const float*)d_in[6];
    const float* dt_w    = (const float*)d_in[7];
    const float* dt_b    = (const float*)d_in[8];
    const float* A_log   = (const float*)d_in[9];
    const float* Dp      = (const float*)d_in[10];
    const float* out_proj= (const float*)d_in[11];
    float* out = (float*)d_out;

    float* ws  = (float*)d_ws;
    float* ln  = ws;                 ws += (size_t)BL * D_MODEL;   // 6.29M
    float* xz  = ws;                 ws += (size_t)BL * 1536;      // 25.2M
    float* xsc = ws;                 ws += (size_t)BL * D_INNER;   // 12.6M
    float* dt  = ws;                 ws += (size_t)BL * D_INNER;   // 12.6M
    float* Bc  = ws;                 ws += (size_t)BL * D_STATE;
    float* Cc  = ws;                 ws += (size_t)BL * D_STATE;

    for (int i = 0; i < 2; i++) {
        const float* hin = (i == 0) ? x : out;
        ln_kernel<<<BL, 384, 0, stream>>>(hin, norm_w + i * D_MODEL,
                                          norm_b + i * D_MODEL, ln);
        gemm_atb<<<dim3(BL / 64, 1536 / 64), 256, 0, stream>>>(
            ln, in_proj + (size_t)i * 1536 * D_MODEL, nullptr, xz,
            BL, 1536, D_MODEL);
        conv_silu_kernel<<<(BL * D_INNER) / 256, 256, 0, stream>>>(
            xz, conv_w + i * D_INNER * K_CONV, conv_b + i * D_INNER, xsc, i);
        xproj_dt_kernel<<<BL, 256, 0, stream>>>(
            xsc, x_proj + (size_t)i * 56 * D_INNER,
            dt_w + (size_t)i * D_INNER * DT_RANK, dt_b + i * D_INNER,
            dt, Bc, Cc);
        scan_kernel<<<BATCH * 3, 256, 0, stream>>>(
            dt, xsc, xz, Bc, Cc, A_log + (size_t)i * D_INNER * D_STATE,
            Dp + i * D_INNER, dt /* y aliases dt */, i);
        gemm_atb<<<dim3(BL / 64, D_MODEL / 64), 256, 0, stream>>>(
            dt, out_proj + (size_t)i * D_MODEL * D_INNER, hin, out,
            BL, D_MODEL, D_INNER);
    }
}

// Round 2
// 2065.766 us; speedup vs baseline: 1.9518x; 1.9518x over previous
//
#include <hip/hip_runtime.h>
#include <hip/hip_bf16.h>
#include <cstddef>

#define D_MODEL 384
#define D_INNER 768
#define D_STATE 16
#define DT_RANK 24
#define K_CONV  4
#define BATCH   8
#define SEQ     2048
#define BL      (BATCH * SEQ)     // 16384 rows
#define NCHUNK  32
#define LCHUNK  (SEQ / NCHUNK)    // 64

// ---------------------------------------------------------------------------
// LayerNorm over last dim (384). One block per row, 384 threads.
// ---------------------------------------------------------------------------
__global__ __launch_bounds__(384) void ln_kernel(
    const float* __restrict__ in, const float* __restrict__ w,
    const float* __restrict__ b, float* __restrict__ out)
{
    int row = blockIdx.x;
    int tid = threadIdx.x;
    float v = in[(size_t)row * D_MODEL + tid];
    float s = v, sq = v * v;
    #pragma unroll
    for (int o = 32; o; o >>= 1) {
        s  += __shfl_down(s, o);
        sq += __shfl_down(sq, o);
    }
    __shared__ float ss[6], ssq[6];
    __shared__ float mb[2];
    int wid = tid >> 6;
    if ((tid & 63) == 0) { ss[wid] = s; ssq[wid] = sq; }
    __syncthreads();
    if (tid == 0) {
        float S = 0.f, Q = 0.f;
        #pragma unroll
        for (int k = 0; k < 6; k++) { S += ss[k]; Q += ssq[k]; }
        float mu  = S * (1.0f / D_MODEL);
        float var = Q * (1.0f / D_MODEL) - mu * mu;
        mb[0] = mu;
        mb[1] = rsqrtf(var + 1e-5f);
    }
    __syncthreads();
    out[(size_t)row * D_MODEL + tid] = (v - mb[0]) * mb[1] * w[tid] + b[tid];
}

// ---------------------------------------------------------------------------
// Generic C = A (MxK) * W^T (W is NxK) [+ resid], all row-major f32.
// 64x64x16 tiles, 256 threads, 4x4 per-thread microtile.
// ---------------------------------------------------------------------------
__global__ __launch_bounds__(256) void gemm_atb(
    const float* __restrict__ A, const float* __restrict__ W,
    const float* resid, float* C, int M, int N, int K)
{
    __shared__ float As[16][68];
    __shared__ float Ws[16][68];
    int bm = blockIdx.x, bn = blockIdx.y;
    int tid = threadIdx.x;
    int tx = tid & 15, ty = tid >> 4;
    int lrow  = tid >> 2;          // 0..63
    int lcol4 = (tid & 3) * 4;     // 0,4,8,12

    const float* Ablk = A + (size_t)(bm * 64) * K;
    const float* Wblk = W + (size_t)(bn * 64) * K;

    float acc[4][4] = {};
    for (int k0 = 0; k0 < K; k0 += 16) {
        float4 av = *(const float4*)(Ablk + (size_t)lrow * K + k0 + lcol4);
        float4 wv = *(const float4*)(Wblk + (size_t)lrow * K + k0 + lcol4);
        As[lcol4 + 0][lrow] = av.x; As[lcol4 + 1][lrow] = av.y;
        As[lcol4 + 2][lrow] = av.z; As[lcol4 + 3][lrow] = av.w;
        Ws[lcol4 + 0][lrow] = wv.x; Ws[lcol4 + 1][lrow] = wv.y;
        Ws[lcol4 + 2][lrow] = wv.z; Ws[lcol4 + 3][lrow] = wv.w;
        __syncthreads();
        #pragma unroll
        for (int kk = 0; kk < 16; kk++) {
            float a[4], bfr[4];
            #pragma unroll
            for (int i = 0; i < 4; i++) a[i]   = As[kk][ty * 4 + i];
            #pragma unroll
            for (int j = 0; j < 4; j++) bfr[j] = Ws[kk][tx * 4 + j];
            #pragma unroll
            for (int i = 0; i < 4; i++)
                #pragma unroll
                for (int j = 0; j < 4; j++)
                    acc[i][j] = fmaf(a[i], bfr[j], acc[i][j]);
        }
        __syncthreads();
    }
    int r0 = bm * 64 + ty * 4;
    int c0 = bn * 64 + tx * 4;
    #pragma unroll
    for (int i = 0; i < 4; i++) {
        #pragma unroll
        for (int j = 0; j < 4; j++) {
            size_t idx = (size_t)(r0 + i) * N + c0 + j;
            float v = acc[i][j];
            if (resid) v += resid[idx];
            C[idx] = v;
        }
    }
}

// ---------------------------------------------------------------------------
// Causal depthwise conv (k=4) + bias + SiLU. dir=0 backward-looking; dir=1
// forward-looking with reversed kernel (== flip-conv-flip).
// ---------------------------------------------------------------------------
__global__ __launch_bounds__(256) void conv_silu_kernel(
    const float* __restrict__ xz, const float* __restrict__ cw,
    const float* __restrict__ cb, float* __restrict__ xsc, int dir)
{
    int idx = blockIdx.x * 256 + threadIdx.x;   // BL * 768
    int c   = idx % D_INNER;
    int row = idx / D_INNER;     // b*SEQ + l
    int l   = row % SEQ;
    int b0  = row - l;
    float acc = cb[c];
    if (dir == 0) {
        #pragma unroll
        for (int k = 0; k < 4; k++) {
            int ls = l - 3 + k;
            if (ls >= 0)
                acc = fmaf(xz[(size_t)(b0 + ls) * 1536 + c], cw[c * 4 + k], acc);
        }
    } else {
        #pragma unroll
        for (int j = 0; j < 4; j++) {
            int ls = l + j;
            if (ls < SEQ)
                acc = fmaf(xz[(size_t)(b0 + ls) * 1536 + c], cw[c * 4 + 3 - j], acc);
        }
    }
    float sg = 1.0f / (1.0f + __expf(-acc));
    xsc[idx] = acc * sg;
}

// ---------------------------------------------------------------------------
// Per-row: x_dbl = xs @ x_proj^T (56 outs), dt = softplus(dt_raw @ dt_w^T +
// dt_b) (768 outs), emit B (16) and C (16). One block per row, 256 threads.
// ---------------------------------------------------------------------------
__global__ __launch_bounds__(256) void xproj_dt_kernel(
    const float* __restrict__ xsc, const float* __restrict__ xproj,
    const float* __restrict__ dtw, const float* __restrict__ dtbias,
    float* __restrict__ dt_out, float* __restrict__ Bc, float* __restrict__ Cc)
{
    __shared__ float xs[D_INNER];
    __shared__ float xd[DT_RANK + 2 * D_STATE];
    int row = blockIdx.x;
    int tid = threadIdx.x;
    const float* xr = xsc + (size_t)row * D_INNER;
    #pragma unroll
    for (int j = 0; j < 3; j++) xs[tid + j * 256] = xr[tid + j * 256];
    __syncthreads();

    int o = tid >> 2, sub = tid & 3;
    if (o < 56) {
        float p = 0.f;
        const float* wr  = xproj + o * D_INNER + sub * 192;
        const float* xrr = xs + sub * 192;
        for (int k = 0; k < 192; k++) p = fmaf(xrr[k], wr[k], p);
        p += __shfl_xor(p, 1);
        p += __shfl_xor(p, 2);
        if (sub == 0) xd[o] = p;
    }
    __syncthreads();

    #pragma unroll
    for (int j = 0; j < 3; j++) {
        int d = tid + j * 256;
        float acc = dtbias[d];
        #pragma unroll
        for (int r = 0; r < DT_RANK; r++)
            acc = fmaf(xd[r], dtw[d * DT_RANK + r], acc);
        float sp = acc > 20.f ? acc : __logf(1.f + __expf(acc));
        dt_out[(size_t)row * D_INNER + d] = sp;
    }
    if (tid < D_STATE)
        Bc[(size_t)row * D_STATE + tid] = xd[DT_RANK + tid];
    else if (tid < 2 * D_STATE)
        Cc[(size_t)row * D_STATE + tid - D_STATE] = xd[DT_RANK + D_STATE + tid - D_STATE];
}

// ---------------------------------------------------------------------------
// Chunked selective scan, pass 1: per-chunk local scan from h=0.
// Emits chunk-final state h_out[16] and sum(dt) per (b,chunk,d) chain.
// Grid: BATCH * NCHUNK * 3 blocks of 256 (one thread per d).
// ---------------------------------------------------------------------------
__global__ __launch_bounds__(256) void scan_pass1(
    const float* __restrict__ dt, const float* __restrict__ xsc,
    const float* __restrict__ Bc, const float* __restrict__ A_log,
    float* __restrict__ hout, float* __restrict__ sumdt_buf, int dir)
{
    int g = blockIdx.x % 3;
    int c = (blockIdx.x / 3) % NCHUNK;
    int b = blockIdx.x / (3 * NCHUNK);
    int d = g * 256 + threadIdx.x;
    float A[D_STATE];
    #pragma unroll
    for (int n = 0; n < D_STATE; n++) A[n] = -__expf(A_log[d * D_STATE + n]);
    float h[D_STATE] = {};
    float sdt = 0.f;
    size_t base = (size_t)b * SEQ;
    for (int i = 0; i < LCHUNK; i++) {
        int p = c * LCHUNK + i;
        int l = dir ? (SEQ - 1 - p) : p;
        size_t row = base + l;
        float dtv = dt[row * D_INNER + d];
        float xv  = xsc[row * D_INNER + d];
        float dtx = dtv * xv;
        sdt += dtv;
        const float* Br = Bc + row * D_STATE;
        #pragma unroll
        for (int n = 0; n < D_STATE; n++)
            h[n] = fmaf(__expf(dtv * A[n]), h[n], dtx * Br[n]);
    }
    size_t cidx = (size_t)(b * NCHUNK + c) * D_INNER + d;
    sumdt_buf[cidx] = sdt;
    #pragma unroll
    for (int n = 0; n < D_STATE; n++) hout[cidx * D_STATE + n] = h[n];
}

// ---------------------------------------------------------------------------
// Pass 2: sequential combine over chunk summaries. One thread per (b,d,n),
// 32 steps. h_in[c] = entry state of chunk c (h_in[0] = 0).
// ---------------------------------------------------------------------------
__global__ __launch_bounds__(256) void scan_pass2(
    const float* __restrict__ hout, const float* __restrict__ sumdt_buf,
    const float* __restrict__ A_log, float* __restrict__ hin)
{
    int gid = blockIdx.x * 256 + threadIdx.x;   // BATCH * D_INNER * 16
    int n = gid & 15;
    int d = (gid >> 4) % D_INNER;
    int b = gid / (16 * D_INNER);
    float A = -__expf(A_log[d * D_STATE + n]);
    float h = 0.f;
    for (int c = 0; c < NCHUNK; c++) {
        size_t cidx = (size_t)(b * NCHUNK + c) * D_INNER + d;
        hin[cidx * D_STATE + n] = h;
        h = fmaf(__expf(A * sumdt_buf[cidx]), h, hout[cidx * D_STATE + n]);
    }
}

// ---------------------------------------------------------------------------
// Pass 3: local scan seeded with h_in; fuses y = h.C + D*x, SiLU(z) gating.
// y may alias dt (same-thread read-before-write per element).
// ---------------------------------------------------------------------------
__global__ __launch_bounds__(256) void scan_pass3(
    const float* dt, const float* __restrict__ xsc,
    const float* __restrict__ xz, const float* __restrict__ Bc,
    const float* __restrict__ Cc, const float* __restrict__ A_log,
    const float* __restrict__ Dp, const float* __restrict__ hin,
    float* y, int dir)
{
    int g = blockIdx.x % 3;
    int c = (blockIdx.x / 3) % NCHUNK;
    int b = blockIdx.x / (3 * NCHUNK);
    int d = g * 256 + threadIdx.x;
    size_t cidx = (size_t)(b * NCHUNK + c) * D_INNER + d;
    float A[D_STATE], h[D_STATE];
    #pragma unroll
    for (int n = 0; n < D_STATE; n++) {
        A[n] = -__expf(A_log[d * D_STATE + n]);
        h[n] = hin[cidx * D_STATE + n];
    }
    float Dd = Dp[d];
    size_t base = (size_t)b * SEQ;
    for (int i = 0; i < LCHUNK; i++) {
        int p = c * LCHUNK + i;
        int l = dir ? (SEQ - 1 - p) : p;
        size_t row = base + l;
        float dtv = dt[row * D_INNER + d];
        float xv  = xsc[row * D_INNER + d];
        float zv  = xz[row * 1536 + D_INNER + d];
        float dtx = dtv * xv;
        const float* Br = Bc + row * D_STATE;
        const float* Cr = Cc + row * D_STATE;
        float yv = 0.f;
        #pragma unroll
        for (int n = 0; n < D_STATE; n++) {
            h[n] = fmaf(__expf(dtv * A[n]), h[n], dtx * Br[n]);
            yv = fmaf(h[n], Cr[n], yv);
        }
        yv = fmaf(xv, Dd, yv);
        float sg = 1.f / (1.f + __expf(-zv));
        yv *= zv * sg;
        y[row * D_INNER + d] = yv;
    }
}

// ---------------------------------------------------------------------------
extern "C" void kernel_launch(void* const* d_in, const int* in_sizes, int n_in,
                              void* d_out, int out_size, void* d_ws, size_t ws_size,
                              hipStream_t stream)
{
    const float* x       = (const float*)d_in[0];
    const float* norm_w  = (const float*)d_in[1];
    const float* norm_b  = (const float*)d_in[2];
    const float* in_proj = (const float*)d_in[3];
    const float* conv_w  = (const float*)d_in[4];
    const float* conv_b  = (const float*)d_in[5];
    const float* x_proj  = (const float*)d_in[6];
    const float* dt_w    = (const float*)d_in[7];
    const float* dt_b    = (const float*)d_in[8];
    const float* A_log   = (const float*)d_in[9];
    const float* Dp      = (const float*)d_in[10];
    const float* out_proj= (const float*)d_in[11];
    float* out = (float*)d_out;

    float* ws  = (float*)d_ws;
    float* ln  = ws;                 ws += (size_t)BL * D_MODEL;
    float* xz  = ws;                 ws += (size_t)BL * 1536;
    float* xsc = ws;                 ws += (size_t)BL * D_INNER;
    float* dt  = ws;                 ws += (size_t)BL * D_INNER;
    float* Bc  = ws;                 ws += (size_t)BL * D_STATE;
    float* Cc  = ws;                 ws += (size_t)BL * D_STATE;
    float* sumdt = ws;               ws += (size_t)BATCH * NCHUNK * D_INNER;
    float* hout  = ws;               ws += (size_t)BATCH * NCHUNK * D_INNER * D_STATE;
    float* hin   = ws;               ws += (size_t)BATCH * NCHUNK * D_INNER * D_STATE;

    for (int i = 0; i < 2; i++) {
        const float* hinp = (i == 0) ? x : out;
        ln_kernel<<<BL, 384, 0, stream>>>(hinp, norm_w + i * D_MODEL,
                                          norm_b + i * D_MODEL, ln);
        gemm_atb<<<dim3(BL / 64, 1536 / 64), 256, 0, stream>>>(
            ln, in_proj + (size_t)i * 1536 * D_MODEL, nullptr, xz,
            BL, 1536, D_MODEL);
        conv_silu_kernel<<<(BL * D_INNER) / 256, 256, 0, stream>>>(
            xz, conv_w + i * D_INNER * K_CONV, conv_b + i * D_INNER, xsc, i);
        xproj_dt_kernel<<<BL, 256, 0, stream>>>(
            xsc, x_proj + (size_t)i * 56 * D_INNER,
            dt_w + (size_t)i * D_INNER * DT_RANK, dt_b + i * D_INNER,
            dt, Bc, Cc);
        scan_pass1<<<BATCH * NCHUNK * 3, 256, 0, stream>>>(
            dt, xsc, Bc, A_log + (size_t)i * D_INNER * D_STATE,
            hout, sumdt, i);
        scan_pass2<<<(BATCH * D_INNER * D_STATE) / 256, 256, 0, stream>>>(
            hout, sumdt, A_log + (size_t)i * D_INNER * D_STATE, hin);
        scan_pass3<<<BATCH * NCHUNK * 3, 256, 0, stream>>>(
            dt, xsc, xz, Bc, Cc, A_log + (size_t)i * D_INNER * D_STATE,
            Dp + i * D_INNER, hin, dt /* y aliases dt */, i);
        gemm_atb<<<dim3(BL / 64, D_MODEL / 64), 256, 0, stream>>>(
            dt, out_proj + (size_t)i * D_MODEL * D_INNER, hinp, out,
            BL, D_MODEL, D_INNER);
    }
}

// Round 3
// 1431.700 us; speedup vs baseline: 2.8162x; 1.4429x over previous
//
#include <hip/hip_runtime.h>
#include <hip/hip_bf16.h>
#include <cstddef>

#define D_MODEL 384
#define D_INNER 768
#define D_STATE 16
#define DT_RANK 24
#define K_CONV  4
#define BATCH   8
#define SEQ     2048
#define BL      (BATCH * SEQ)     // 16384 rows
#define NCHUNK  32
#define LCHUNK  (SEQ / NCHUNK)    // 64
#define XDBL_LD 64                // padded leading dim of x_dbl buffer
#define DTROWS  16                // rows per dt_kernel block

// ---------------------------------------------------------------------------
// LayerNorm over last dim (384). One block per row, 384 threads.
// ---------------------------------------------------------------------------
__global__ __launch_bounds__(384) void ln_kernel(
    const float* __restrict__ in, const float* __restrict__ w,
    const float* __restrict__ b, float* __restrict__ out)
{
    int row = blockIdx.x;
    int tid = threadIdx.x;
    float v = in[(size_t)row * D_MODEL + tid];
    float s = v, sq = v * v;
    #pragma unroll
    for (int o = 32; o; o >>= 1) {
        s  += __shfl_down(s, o);
        sq += __shfl_down(sq, o);
    }
    __shared__ float ss[6], ssq[6];
    __shared__ float mb[2];
    int wid = tid >> 6;
    if ((tid & 63) == 0) { ss[wid] = s; ssq[wid] = sq; }
    __syncthreads();
    if (tid == 0) {
        float S = 0.f, Q = 0.f;
        #pragma unroll
        for (int k = 0; k < 6; k++) { S += ss[k]; Q += ssq[k]; }
        float mu  = S * (1.0f / D_MODEL);
        float var = Q * (1.0f / D_MODEL) - mu * mu;
        mb[0] = mu;
        mb[1] = rsqrtf(var + 1e-5f);
    }
    __syncthreads();
    out[(size_t)row * D_MODEL + tid] = (v - mb[0]) * mb[1] * w[tid] + b[tid];
}

// ---------------------------------------------------------------------------
// Generic C = A (MxK) * W^T (W is NxK) [+ resid], all row-major f32.
// 64x64x16 tiles, 256 threads, 4x4 per-thread microtile.
// ---------------------------------------------------------------------------
__global__ __launch_bounds__(256) void gemm_atb(
    const float* __restrict__ A, const float* __restrict__ W,
    const float* resid, float* C, int M, int N, int K)
{
    __shared__ float As[16][68];
    __shared__ float Ws[16][68];
    int bm = blockIdx.x, bn = blockIdx.y;
    int tid = threadIdx.x;
    int tx = tid & 15, ty = tid >> 4;
    int lrow  = tid >> 2;          // 0..63
    int lcol4 = (tid & 3) * 4;     // 0,4,8,12

    const float* Ablk = A + (size_t)(bm * 64) * K;
    const float* Wblk = W + (size_t)(bn * 64) * K;

    float acc[4][4] = {};
    for (int k0 = 0; k0 < K; k0 += 16) {
        float4 av = *(const float4*)(Ablk + (size_t)lrow * K + k0 + lcol4);
        float4 wv = *(const float4*)(Wblk + (size_t)lrow * K + k0 + lcol4);
        As[lcol4 + 0][lrow] = av.x; As[lcol4 + 1][lrow] = av.y;
        As[lcol4 + 2][lrow] = av.z; As[lcol4 + 3][lrow] = av.w;
        Ws[lcol4 + 0][lrow] = wv.x; Ws[lcol4 + 1][lrow] = wv.y;
        Ws[lcol4 + 2][lrow] = wv.z; Ws[lcol4 + 3][lrow] = wv.w;
        __syncthreads();
        #pragma unroll
        for (int kk = 0; kk < 16; kk++) {
            float a[4], bfr[4];
            #pragma unroll
            for (int i = 0; i < 4; i++) a[i]   = As[kk][ty * 4 + i];
            #pragma unroll
            for (int j = 0; j < 4; j++) bfr[j] = Ws[kk][tx * 4 + j];
            #pragma unroll
            for (int i = 0; i < 4; i++)
                #pragma unroll
                for (int j = 0; j < 4; j++)
                    acc[i][j] = fmaf(a[i], bfr[j], acc[i][j]);
        }
        __syncthreads();
    }
    int r0 = bm * 64 + ty * 4;
    int c0 = bn * 64 + tx * 4;
    #pragma unroll
    for (int i = 0; i < 4; i++) {
        #pragma unroll
        for (int j = 0; j < 4; j++) {
            size_t idx = (size_t)(r0 + i) * N + c0 + j;
            float v = acc[i][j];
            if (resid) v += resid[idx];
            C[idx] = v;
        }
    }
}

// ---------------------------------------------------------------------------
// x_dbl = xs @ x_proj^T as a proper tiled GEMM. N padded 56 -> 64 (zero rows).
// Output: BL x 64 buffer (cols 0..23 dt_raw, 24..39 B, 40..55 C).
// ---------------------------------------------------------------------------
__global__ __launch_bounds__(256) void xdbl_gemm(
    const float* __restrict__ A, const float* __restrict__ W,
    float* __restrict__ C)
{
    __shared__ float As[16][68];
    __shared__ float Ws[16][68];
    int bm = blockIdx.x;
    int tid = threadIdx.x;
    int tx = tid & 15, ty = tid >> 4;
    int lrow  = tid >> 2;
    int lcol4 = (tid & 3) * 4;

    const float* Ablk = A + (size_t)(bm * 64) * D_INNER;

    float acc[4][4] = {};
    for (int k0 = 0; k0 < D_INNER; k0 += 16) {
        float4 av = *(const float4*)(Ablk + (size_t)lrow * D_INNER + k0 + lcol4);
        float4 wv = make_float4(0.f, 0.f, 0.f, 0.f);
        if (lrow < 56)
            wv = *(const float4*)(W + (size_t)lrow * D_INNER + k0 + lcol4);
        As[lcol4 + 0][lrow] = av.x; As[lcol4 + 1][lrow] = av.y;
        As[lcol4 + 2][lrow] = av.z; As[lcol4 + 3][lrow] = av.w;
        Ws[lcol4 + 0][lrow] = wv.x; Ws[lcol4 + 1][lrow] = wv.y;
        Ws[lcol4 + 2][lrow] = wv.z; Ws[lcol4 + 3][lrow] = wv.w;
        __syncthreads();
        #pragma unroll
        for (int kk = 0; kk < 16; kk++) {
            float a[4], bfr[4];
            #pragma unroll
            for (int i = 0; i < 4; i++) a[i]   = As[kk][ty * 4 + i];
            #pragma unroll
            for (int j = 0; j < 4; j++) bfr[j] = Ws[kk][tx * 4 + j];
            #pragma unroll
            for (int i = 0; i < 4; i++)
                #pragma unroll
                for (int j = 0; j < 4; j++)
                    acc[i][j] = fmaf(a[i], bfr[j], acc[i][j]);
        }
        __syncthreads();
    }
    int r0 = bm * 64 + ty * 4;
    int c0 = tx * 4;
    #pragma unroll
    for (int i = 0; i < 4; i++)
        #pragma unroll
        for (int j = 0; j < 4; j++)
            C[(size_t)(r0 + i) * XDBL_LD + c0 + j] = acc[i][j];
}

// ---------------------------------------------------------------------------
// dt = softplus(dt_raw @ dt_w^T + dt_b). K=24: weights in VGPRs, x_dbl rows
// broadcast from LDS. Block: 256 threads = one 256-wide d slice, DTROWS rows.
// Grid: (BL/DTROWS) * 3.
// ---------------------------------------------------------------------------
__global__ __launch_bounds__(256) void dt_kernel(
    const float* __restrict__ xdbl, const float* __restrict__ dtw,
    const float* __restrict__ dtbias, float* __restrict__ dt_out)
{
    int g    = blockIdx.x % 3;
    int row0 = (blockIdx.x / 3) * DTROWS;
    int tid  = threadIdx.x;
    int d    = g * 256 + tid;
    float w[DT_RANK];
    #pragma unroll
    for (int r = 0; r < DT_RANK; r++) w[r] = dtw[d * DT_RANK + r];
    float bias = dtbias[d];
    __shared__ float xd[DTROWS][DT_RANK];
    for (int i = tid; i < DTROWS * DT_RANK; i += 256) {
        int rr = i / DT_RANK, cc = i % DT_RANK;
        xd[rr][cc] = xdbl[(size_t)(row0 + rr) * XDBL_LD + cc];
    }
    __syncthreads();
    #pragma unroll 4
    for (int i = 0; i < DTROWS; i++) {
        float acc = bias;
        #pragma unroll
        for (int r = 0; r < DT_RANK; r++) acc = fmaf(xd[i][r], w[r], acc);
        float sp = acc > 20.f ? acc : __logf(1.f + __expf(acc));
        dt_out[(size_t)(row0 + i) * D_INNER + d] = sp;
    }
}

// ---------------------------------------------------------------------------
// Causal depthwise conv (k=4) + bias + SiLU. dir=0 backward-looking; dir=1
// forward-looking with reversed kernel (== flip-conv-flip).
// ---------------------------------------------------------------------------
__global__ __launch_bounds__(256) void conv_silu_kernel(
    const float* __restrict__ xz, const float* __restrict__ cw,
    const float* __restrict__ cb, float* __restrict__ xsc, int dir)
{
    int idx = blockIdx.x * 256 + threadIdx.x;   // BL * 768
    int c   = idx % D_INNER;
    int row = idx / D_INNER;     // b*SEQ + l
    int l   = row % SEQ;
    int b0  = row - l;
    float acc = cb[c];
    if (dir == 0) {
        #pragma unroll
        for (int k = 0; k < 4; k++) {
            int ls = l - 3 + k;
            if (ls >= 0)
                acc = fmaf(xz[(size_t)(b0 + ls) * 1536 + c], cw[c * 4 + k], acc);
        }
    } else {
        #pragma unroll
        for (int j = 0; j < 4; j++) {
            int ls = l + j;
            if (ls < SEQ)
                acc = fmaf(xz[(size_t)(b0 + ls) * 1536 + c], cw[c * 4 + 3 - j], acc);
        }
    }
    float sg = 1.0f / (1.0f + __expf(-acc));
    xsc[idx] = acc * sg;
}

// ---------------------------------------------------------------------------
// Chunked selective scan, pass 1: per-chunk local scan from h=0.
// B comes from x_dbl cols 24..39 (stride XDBL_LD).
// ---------------------------------------------------------------------------
__global__ __launch_bounds__(256) void scan_pass1(
    const float* __restrict__ dt, const float* __restrict__ xsc,
    const float* __restrict__ xdbl, const float* __restrict__ A_log,
    float* __restrict__ hout, float* __restrict__ sumdt_buf, int dir)
{
    int g = blockIdx.x % 3;
    int c = (blockIdx.x / 3) % NCHUNK;
    int b = blockIdx.x / (3 * NCHUNK);
    int d = g * 256 + threadIdx.x;
    float A[D_STATE];
    #pragma unroll
    for (int n = 0; n < D_STATE; n++) A[n] = -__expf(A_log[d * D_STATE + n]);
    float h[D_STATE] = {};
    float sdt = 0.f;
    size_t base = (size_t)b * SEQ;
    for (int i = 0; i < LCHUNK; i++) {
        int p = c * LCHUNK + i;
        int l = dir ? (SEQ - 1 - p) : p;
        size_t row = base + l;
        float dtv = dt[row * D_INNER + d];
        float xv  = xsc[row * D_INNER + d];
        float dtx = dtv * xv;
        sdt += dtv;
        const float* Br = xdbl + row * XDBL_LD + DT_RANK;
        #pragma unroll
        for (int n = 0; n < D_STATE; n++)
            h[n] = fmaf(__expf(dtv * A[n]), h[n], dtx * Br[n]);
    }
    size_t cidx = (size_t)(b * NCHUNK + c) * D_INNER + d;
    sumdt_buf[cidx] = sdt;
    #pragma unroll
    for (int n = 0; n < D_STATE; n++) hout[cidx * D_STATE + n] = h[n];
}

// ---------------------------------------------------------------------------
// Pass 2: sequential combine over chunk summaries. One thread per (b,d,n).
// ---------------------------------------------------------------------------
__global__ __launch_bounds__(256) void scan_pass2(
    const float* __restrict__ hout, const float* __restrict__ sumdt_buf,
    const float* __restrict__ A_log, float* __restrict__ hin)
{
    int gid = blockIdx.x * 256 + threadIdx.x;   // BATCH * D_INNER * 16
    int n = gid & 15;
    int d = (gid >> 4) % D_INNER;
    int b = gid / (16 * D_INNER);
    float A = -__expf(A_log[d * D_STATE + n]);
    float h = 0.f;
    for (int c = 0; c < NCHUNK; c++) {
        size_t cidx = (size_t)(b * NCHUNK + c) * D_INNER + d;
        hin[cidx * D_STATE + n] = h;
        h = fmaf(__expf(A * sumdt_buf[cidx]), h, hout[cidx * D_STATE + n]);
    }
}

// ---------------------------------------------------------------------------
// Pass 3: local scan seeded with h_in; fuses y = h.C + D*x, SiLU(z) gating.
// B/C from x_dbl cols 24..39 / 40..55. y may alias dt.
// ---------------------------------------------------------------------------
__global__ __launch_bounds__(256) void scan_pass3(
    const float* dt, const float* __restrict__ xsc,
    const float* __restrict__ xz, const float* __restrict__ xdbl,
    const float* __restrict__ A_log, const float* __restrict__ Dp,
    const float* __restrict__ hin, float* y, int dir)
{
    int g = blockIdx.x % 3;
    int c = (blockIdx.x / 3) % NCHUNK;
    int b = blockIdx.x / (3 * NCHUNK);
    int d = g * 256 + threadIdx.x;
    size_t cidx = (size_t)(b * NCHUNK + c) * D_INNER + d;
    float A[D_STATE], h[D_STATE];
    #pragma unroll
    for (int n = 0; n < D_STATE; n++) {
        A[n] = -__expf(A_log[d * D_STATE + n]);
        h[n] = hin[cidx * D_STATE + n];
    }
    float Dd = Dp[d];
    size_t base = (size_t)b * SEQ;
    for (int i = 0; i < LCHUNK; i++) {
        int p = c * LCHUNK + i;
        int l = dir ? (SEQ - 1 - p) : p;
        size_t row = base + l;
        float dtv = dt[row * D_INNER + d];
        float xv  = xsc[row * D_INNER + d];
        float zv  = xz[row * 1536 + D_INNER + d];
        float dtx = dtv * xv;
        const float* Br = xdbl + row * XDBL_LD + DT_RANK;
        const float* Cr = Br + D_STATE;
        float yv = 0.f;
        #pragma unroll
        for (int n = 0; n < D_STATE; n++) {
            h[n] = fmaf(__expf(dtv * A[n]), h[n], dtx * Br[n]);
            yv = fmaf(h[n], Cr[n], yv);
        }
        yv = fmaf(xv, Dd, yv);
        float sg = 1.f / (1.f + __expf(-zv));
        yv *= zv * sg;
        y[row * D_INNER + d] = yv;
    }
}

// ---------------------------------------------------------------------------
extern "C" void kernel_launch(void* const* d_in, const int* in_sizes, int n_in,
                              void* d_out, int out_size, void* d_ws, size_t ws_size,
                              hipStream_t stream)
{
    const float* x       = (const float*)d_in[0];
    const float* norm_w  = (const float*)d_in[1];
    const float* norm_b  = (const float*)d_in[2];
    const float* in_proj = (const float*)d_in[3];
    const float* conv_w  = (const float*)d_in[4];
    const float* conv_b  = (const float*)d_in[5];
    const float* x_proj  = (const float*)d_in[6];
    const float* dt_w    = (const float*)d_in[7];
    const float* dt_b    = (const float*)d_in[8];
    const float* A_log   = (const float*)d_in[9];
    const float* Dp      = (const float*)d_in[10];
    const float* out_proj= (const float*)d_in[11];
    float* out = (float*)d_out;

    float* ws  = (float*)d_ws;
    float* ln   = ws;                ws += (size_t)BL * D_MODEL;
    float* xz   = ws;                ws += (size_t)BL * 1536;
    float* xsc  = ws;                ws += (size_t)BL * D_INNER;
    float* dt   = ws;                ws += (size_t)BL * D_INNER;
    float* xdbl = ws;                ws += (size_t)BL * XDBL_LD;
    float* sumdt = ws;               ws += (size_t)BATCH * NCHUNK * D_INNER;
    float* hout  = ws;               ws += (size_t)BATCH * NCHUNK * D_INNER * D_STATE;
    float* hin   = ws;               ws += (size_t)BATCH * NCHUNK * D_INNER * D_STATE;

    for (int i = 0; i < 2; i++) {
        const float* hinp = (i == 0) ? x : out;
        ln_kernel<<<BL, 384, 0, stream>>>(hinp, norm_w + i * D_MODEL,
                                          norm_b + i * D_MODEL, ln);
        gemm_atb<<<dim3(BL / 64, 1536 / 64), 256, 0, stream>>>(
            ln, in_proj + (size_t)i * 1536 * D_MODEL, nullptr, xz,
            BL, 1536, D_MODEL);
        conv_silu_kernel<<<(BL * D_INNER) / 256, 256, 0, stream>>>(
            xz, conv_w + i * D_INNER * K_CONV, conv_b + i * D_INNER, xsc, i);
        xdbl_gemm<<<BL / 64, 256, 0, stream>>>(
            xsc, x_proj + (size_t)i * 56 * D_INNER, xdbl);
        dt_kernel<<<(BL / DTROWS) * 3, 256, 0, stream>>>(
            xdbl, dt_w + (size_t)i * D_INNER * DT_RANK, dt_b + i * D_INNER, dt);
        scan_pass1<<<BATCH * NCHUNK * 3, 256, 0, stream>>>(
            dt, xsc, xdbl, A_log + (size_t)i * D_INNER * D_STATE,
            hout, sumdt, i);
        scan_pass2<<<(BATCH * D_INNER * D_STATE) / 256, 256, 0, stream>>>(
            hout, sumdt, A_log + (size_t)i * D_INNER * D_STATE, hin);
        scan_pass3<<<BATCH * NCHUNK * 3, 256, 0, stream>>>(
            dt, xsc, xz, xdbl, A_log + (size_t)i * D_INNER * D_STATE,
            Dp + i * D_INNER, hin, dt /* y aliases dt */, i);
        gemm_atb<<<dim3(BL / 64, D_MODEL / 64), 256, 0, stream>>>(
            dt, out_proj + (size_t)i * D_MODEL * D_INNER, hinp, out,
            BL, D_MODEL, D_INNER);
    }
}

// Round 4
// 782.200 us; speedup vs baseline: 5.1547x; 1.8304x over previous
//
#include <hip/hip_runtime.h>
#include <hip/hip_bf16.h>
#include <cstddef>

#define D_MODEL 384
#define D_INNER 768
#define D_STATE 16
#define DT_RANK 24
#define K_CONV  4
#define BATCH   8
#define SEQ     2048
#define BL      (BATCH * SEQ)     // 16384 rows
#define NCHUNK  32
#define LCHUNK  (SEQ / NCHUNK)    // 64
#define XDBL_LD 64                // padded leading dim of x_dbl buffer
#define DTROWS  16                // rows per dt_kernel block

typedef unsigned short ushort_t;
typedef __bf16 bf16x8 __attribute__((ext_vector_type(8)));
typedef float  f32x4  __attribute__((ext_vector_type(4)));

#define GLOBAL_AS(p) ((const __attribute__((address_space(1))) void*)(p))
#define LDS_AS(p)    ((__attribute__((address_space(3))) void*)(p))

__device__ __forceinline__ ushort_t f32_to_bf16_rne(float v) {
    unsigned int u = __float_as_uint(v);
    return (ushort_t)((u + 0x7FFFu + ((u >> 16) & 1u)) >> 16);
}

// ---------------------------------------------------------------------------
// Elementwise f32 -> bf16 (RNE) for weights.
// ---------------------------------------------------------------------------
__global__ __launch_bounds__(256) void cast_bf16_kernel(
    const float* __restrict__ in, ushort_t* __restrict__ out, int n)
{
    int i = blockIdx.x * 256 + threadIdx.x;
    if (i < n) out[i] = f32_to_bf16_rne(in[i]);
}

// ---------------------------------------------------------------------------
// LayerNorm over last dim (384), output bf16. One block per row, 384 thr.
// ---------------------------------------------------------------------------
__global__ __launch_bounds__(384) void ln_kernel(
    const float* __restrict__ in, const float* __restrict__ w,
    const float* __restrict__ b, ushort_t* __restrict__ out)
{
    int row = blockIdx.x;
    int tid = threadIdx.x;
    float v = in[(size_t)row * D_MODEL + tid];
    float s = v, sq = v * v;
    #pragma unroll
    for (int o = 32; o; o >>= 1) {
        s  += __shfl_down(s, o);
        sq += __shfl_down(sq, o);
    }
    __shared__ float ss[6], ssq[6];
    __shared__ float mb[2];
    int wid = tid >> 6;
    if ((tid & 63) == 0) { ss[wid] = s; ssq[wid] = sq; }
    __syncthreads();
    if (tid == 0) {
        float S = 0.f, Q = 0.f;
        #pragma unroll
        for (int k = 0; k < 6; k++) { S += ss[k]; Q += ssq[k]; }
        float mu  = S * (1.0f / D_MODEL);
        float var = Q * (1.0f / D_MODEL) - mu * mu;
        mb[0] = mu;
        mb[1] = rsqrtf(var + 1e-5f);
    }
    __syncthreads();
    float r = (v - mb[0]) * mb[1] * w[tid] + b[tid];
    out[(size_t)row * D_MODEL + tid] = f32_to_bf16_rne(r);
}

// ---------------------------------------------------------------------------
// bf16 MFMA GEMM: C = A (MxK bf16) * W^T (W NxK bf16) [+ resid(f32)], C f32.
// 128x128 tile, BK=32, 256 threads = 4 waves, each wave owns a 64x64
// quadrant (4x4 grid of 16x16x32 MFMAs). Staging via global_load_lds w=16;
// LDS tiles row-major unpadded (required: wave-uniform dst + lane*16).
// ---------------------------------------------------------------------------
__global__ __launch_bounds__(256) void gemm_mfma(
    const ushort_t* __restrict__ A, const ushort_t* __restrict__ W,
    const float* resid, float* C, int N, int K)
{
    __shared__ __bf16 As[128 * 32];
    __shared__ __bf16 Ws[128 * 32];
    int tid  = threadIdx.x;
    int bm = blockIdx.x, bn = blockIdx.y;
    int lane = tid & 63, wave = tid >> 6;
    int wr = wave >> 1, wc = wave & 1;
    int quad = lane >> 4, l16 = lane & 15;

    // staging addresses: thread t -> LDS elems [t*8, t*8+8) (and +2048 for
    // the second 64-row half); global row = 128*bm + t/4 (+64), col = (t&3)*8
    const ushort_t* Ag = A + (size_t)(bm * 128 + (tid >> 2)) * K + (tid & 3) * 8;
    const ushort_t* Wg = W + (size_t)(bn * 128 + (tid >> 2)) * K + (tid & 3) * 8;

    f32x4 acc[4][4] = {};

    for (int k0 = 0; k0 < K; k0 += 32) {
        __syncthreads();
        __builtin_amdgcn_global_load_lds(GLOBAL_AS(Ag + k0),
                                         LDS_AS(As + tid * 8), 16, 0, 0);
        __builtin_amdgcn_global_load_lds(GLOBAL_AS(Ag + (size_t)64 * K + k0),
                                         LDS_AS(As + 2048 + tid * 8), 16, 0, 0);
        __builtin_amdgcn_global_load_lds(GLOBAL_AS(Wg + k0),
                                         LDS_AS(Ws + tid * 8), 16, 0, 0);
        __builtin_amdgcn_global_load_lds(GLOBAL_AS(Wg + (size_t)64 * K + k0),
                                         LDS_AS(Ws + 2048 + tid * 8), 16, 0, 0);
        __syncthreads();

        bf16x8 af[4], wf[4];
        #pragma unroll
        for (int i = 0; i < 4; i++)
            af[i] = *(const bf16x8*)(As + (wr * 64 + i * 16 + l16) * 32 + quad * 8);
        #pragma unroll
        for (int j = 0; j < 4; j++)
            wf[j] = *(const bf16x8*)(Ws + (wc * 64 + j * 16 + l16) * 32 + quad * 8);
        #pragma unroll
        for (int i = 0; i < 4; i++)
            #pragma unroll
            for (int j = 0; j < 4; j++)
                acc[i][j] = __builtin_amdgcn_mfma_f32_16x16x32_bf16(
                    af[i], wf[j], acc[i][j], 0, 0, 0);
    }

    // C/D layout (16x16x32): col = lane&15, row = quad*4 + reg
    #pragma unroll
    for (int i = 0; i < 4; i++) {
        #pragma unroll
        for (int r = 0; r < 4; r++) {
            int row = bm * 128 + wr * 64 + i * 16 + quad * 4 + r;
            #pragma unroll
            for (int j = 0; j < 4; j++) {
                int col = bn * 128 + wc * 64 + j * 16 + l16;
                size_t idx = (size_t)row * N + col;
                float v = acc[i][j][r];
                if (resid) v += resid[idx];
                C[idx] = v;
            }
        }
    }
}

// ---------------------------------------------------------------------------
// x_dbl = xs @ x_proj^T, f32 tiled GEMM. N padded 56 -> 64 (zero rows).
// ---------------------------------------------------------------------------
__global__ __launch_bounds__(256) void xdbl_gemm(
    const float* __restrict__ A, const float* __restrict__ W,
    float* __restrict__ C)
{
    __shared__ float As[16][68];
    __shared__ float Ws[16][68];
    int bm = blockIdx.x;
    int tid = threadIdx.x;
    int tx = tid & 15, ty = tid >> 4;
    int lrow  = tid >> 2;
    int lcol4 = (tid & 3) * 4;

    const float* Ablk = A + (size_t)(bm * 64) * D_INNER;

    float acc[4][4] = {};
    for (int k0 = 0; k0 < D_INNER; k0 += 16) {
        float4 av = *(const float4*)(Ablk + (size_t)lrow * D_INNER + k0 + lcol4);
        float4 wv = make_float4(0.f, 0.f, 0.f, 0.f);
        if (lrow < 56)
            wv = *(const float4*)(W + (size_t)lrow * D_INNER + k0 + lcol4);
        As[lcol4 + 0][lrow] = av.x; As[lcol4 + 1][lrow] = av.y;
        As[lcol4 + 2][lrow] = av.z; As[lcol4 + 3][lrow] = av.w;
        Ws[lcol4 + 0][lrow] = wv.x; Ws[lcol4 + 1][lrow] = wv.y;
        Ws[lcol4 + 2][lrow] = wv.z; Ws[lcol4 + 3][lrow] = wv.w;
        __syncthreads();
        #pragma unroll
        for (int kk = 0; kk < 16; kk++) {
            float a[4], bfr[4];
            #pragma unroll
            for (int i = 0; i < 4; i++) a[i]   = As[kk][ty * 4 + i];
            #pragma unroll
            for (int j = 0; j < 4; j++) bfr[j] = Ws[kk][tx * 4 + j];
            #pragma unroll
            for (int i = 0; i < 4; i++)
                #pragma unroll
                for (int j = 0; j < 4; j++)
                    acc[i][j] = fmaf(a[i], bfr[j], acc[i][j]);
        }
        __syncthreads();
    }
    int r0 = bm * 64 + ty * 4;
    int c0 = tx * 4;
    #pragma unroll
    for (int i = 0; i < 4; i++)
        #pragma unroll
        for (int j = 0; j < 4; j++)
            C[(size_t)(r0 + i) * XDBL_LD + c0 + j] = acc[i][j];
}

// ---------------------------------------------------------------------------
// dt = softplus(dt_raw @ dt_w^T + dt_b). K=24 in VGPRs, rows from LDS.
// ---------------------------------------------------------------------------
__global__ __launch_bounds__(256) void dt_kernel(
    const float* __restrict__ xdbl, const float* __restrict__ dtw,
    const float* __restrict__ dtbias, float* __restrict__ dt_out)
{
    int g    = blockIdx.x % 3;
    int row0 = (blockIdx.x / 3) * DTROWS;
    int tid  = threadIdx.x;
    int d    = g * 256 + tid;
    float w[DT_RANK];
    #pragma unroll
    for (int r = 0; r < DT_RANK; r++) w[r] = dtw[d * DT_RANK + r];
    float bias = dtbias[d];
    __shared__ float xd[DTROWS][DT_RANK];
    for (int i = tid; i < DTROWS * DT_RANK; i += 256) {
        int rr = i / DT_RANK, cc = i % DT_RANK;
        xd[rr][cc] = xdbl[(size_t)(row0 + rr) * XDBL_LD + cc];
    }
    __syncthreads();
    #pragma unroll 4
    for (int i = 0; i < DTROWS; i++) {
        float acc = bias;
        #pragma unroll
        for (int r = 0; r < DT_RANK; r++) acc = fmaf(xd[i][r], w[r], acc);
        float sp = acc > 20.f ? acc : __logf(1.f + __expf(acc));
        dt_out[(size_t)(row0 + i) * D_INNER + d] = sp;
    }
}

// ---------------------------------------------------------------------------
// Causal depthwise conv (k=4) + bias + SiLU. dir=0 backward-looking; dir=1
// forward-looking with reversed kernel (== flip-conv-flip).
// ---------------------------------------------------------------------------
__global__ __launch_bounds__(256) void conv_silu_kernel(
    const float* __restrict__ xz, const float* __restrict__ cw,
    const float* __restrict__ cb, float* __restrict__ xsc, int dir)
{
    int idx = blockIdx.x * 256 + threadIdx.x;   // BL * 768
    int c   = idx % D_INNER;
    int row = idx / D_INNER;     // b*SEQ + l
    int l   = row % SEQ;
    int b0  = row - l;
    float acc = cb[c];
    if (dir == 0) {
        #pragma unroll
        for (int k = 0; k < 4; k++) {
            int ls = l - 3 + k;
            if (ls >= 0)
                acc = fmaf(xz[(size_t)(b0 + ls) * 1536 + c], cw[c * 4 + k], acc);
        }
    } else {
        #pragma unroll
        for (int j = 0; j < 4; j++) {
            int ls = l + j;
            if (ls < SEQ)
                acc = fmaf(xz[(size_t)(b0 + ls) * 1536 + c], cw[c * 4 + 3 - j], acc);
        }
    }
    float sg = 1.0f / (1.0f + __expf(-acc));
    xsc[idx] = acc * sg;
}

// ---------------------------------------------------------------------------
// Chunked selective scan, pass 1: per-chunk local scan from h=0.
// ---------------------------------------------------------------------------
__global__ __launch_bounds__(256) void scan_pass1(
    const float* __restrict__ dt, const float* __restrict__ xsc,
    const float* __restrict__ xdbl, const float* __restrict__ A_log,
    float* __restrict__ hstate, float* __restrict__ sumdt_buf, int dir)
{
    int g = blockIdx.x % 3;
    int c = (blockIdx.x / 3) % NCHUNK;
    int b = blockIdx.x / (3 * NCHUNK);
    int d = g * 256 + threadIdx.x;
    float A[D_STATE];
    #pragma unroll
    for (int n = 0; n < D_STATE; n++) A[n] = -__expf(A_log[d * D_STATE + n]);
    float h[D_STATE] = {};
    float sdt = 0.f;
    size_t base = (size_t)b * SEQ;
    for (int i = 0; i < LCHUNK; i++) {
        int p = c * LCHUNK + i;
        int l = dir ? (SEQ - 1 - p) : p;
        size_t row = base + l;
        float dtv = dt[row * D_INNER + d];
        float xv  = xsc[row * D_INNER + d];
        float dtx = dtv * xv;
        sdt += dtv;
        const float* Br = xdbl + row * XDBL_LD + DT_RANK;
        #pragma unroll
        for (int n = 0; n < D_STATE; n++)
            h[n] = fmaf(__expf(dtv * A[n]), h[n], dtx * Br[n]);
    }
    size_t cidx = (size_t)(b * NCHUNK + c) * D_INNER + d;
    sumdt_buf[cidx] = sdt;
    #pragma unroll
    for (int n = 0; n < D_STATE; n++) hstate[cidx * D_STATE + n] = h[n];
}

// ---------------------------------------------------------------------------
// Pass 2: in-place combine; hstate[c] becomes the ENTRY state of chunk c.
// ---------------------------------------------------------------------------
__global__ __launch_bounds__(256) void scan_pass2(
    float* __restrict__ hstate, const float* __restrict__ sumdt_buf,
    const float* __restrict__ A_log)
{
    int gid = blockIdx.x * 256 + threadIdx.x;   // BATCH * D_INNER * 16
    int n = gid & 15;
    int d = (gid >> 4) % D_INNER;
    int b = gid / (16 * D_INNER);
    float A = -__expf(A_log[d * D_STATE + n]);
    float h = 0.f;
    for (int c = 0; c < NCHUNK; c++) {
        size_t cidx = (size_t)(b * NCHUNK + c) * D_INNER + d;
        float ho = hstate[cidx * D_STATE + n];
        hstate[cidx * D_STATE + n] = h;
        h = fmaf(__expf(A * sumdt_buf[cidx]), h, ho);
    }
}

// ---------------------------------------------------------------------------
// Pass 3: local scan seeded with entry state; fuses y = h.C + D*x and
// SiLU(z) gating; emits y in bf16 for the MFMA out-projection.
// ---------------------------------------------------------------------------
__global__ __launch_bounds__(256) void scan_pass3(
    const float* __restrict__ dt, const float* __restrict__ xsc,
    const float* __restrict__ xz, const float* __restrict__ xdbl,
    const float* __restrict__ A_log, const float* __restrict__ Dp,
    const float* __restrict__ hstate, ushort_t* __restrict__ y, int dir)
{
    int g = blockIdx.x % 3;
    int c = (blockIdx.x / 3) % NCHUNK;
    int b = blockIdx.x / (3 * NCHUNK);
    int d = g * 256 + threadIdx.x;
    size_t cidx = (size_t)(b * NCHUNK + c) * D_INNER + d;
    float A[D_STATE], h[D_STATE];
    #pragma unroll
    for (int n = 0; n < D_STATE; n++) {
        A[n] = -__expf(A_log[d * D_STATE + n]);
        h[n] = hstate[cidx * D_STATE + n];
    }
    float Dd = Dp[d];
    size_t base = (size_t)b * SEQ;
    for (int i = 0; i < LCHUNK; i++) {
        int p = c * LCHUNK + i;
        int l = dir ? (SEQ - 1 - p) : p;
        size_t row = base + l;
        float dtv = dt[row * D_INNER + d];
        float xv  = xsc[row * D_INNER + d];
        float zv  = xz[row * 1536 + D_INNER + d];
        float dtx = dtv * xv;
        const float* Br = xdbl + row * XDBL_LD + DT_RANK;
        const float* Cr = Br + D_STATE;
        float yv = 0.f;
        #pragma unroll
        for (int n = 0; n < D_STATE; n++) {
            h[n] = fmaf(__expf(dtv * A[n]), h[n], dtx * Br[n]);
            yv = fmaf(h[n], Cr[n], yv);
        }
        yv = fmaf(xv, Dd, yv);
        float sg = 1.f / (1.f + __expf(-zv));
        yv *= zv * sg;
        y[row * D_INNER + d] = f32_to_bf16_rne(yv);
    }
}

// ---------------------------------------------------------------------------
extern "C" void kernel_launch(void* const* d_in, const int* in_sizes, int n_in,
                              void* d_out, int out_size, void* d_ws, size_t ws_size,
                              hipStream_t stream)
{
    const float* x       = (const float*)d_in[0];
    const float* norm_w  = (const float*)d_in[1];
    const float* norm_b  = (const float*)d_in[2];
    const float* in_proj = (const float*)d_in[3];
    const float* conv_w  = (const float*)d_in[4];
    const float* conv_b  = (const float*)d_in[5];
    const float* x_proj  = (const float*)d_in[6];
    const float* dt_w    = (const float*)d_in[7];
    const float* dt_b    = (const float*)d_in[8];
    const float* A_log   = (const float*)d_in[9];
    const float* Dp      = (const float*)d_in[10];
    const float* out_proj= (const float*)d_in[11];
    float* out = (float*)d_out;

    float* ws   = (float*)d_ws;
    // lnb (bf16, BL*384) and ybf (bf16, BL*768) share one region:
    // lnb dead before ybf written; ybf dead before next direction's lnb.
    float* reg0 = ws;                ws += (size_t)BL * D_INNER / 2;
    ushort_t* lnb = (ushort_t*)reg0;
    ushort_t* ybf = (ushort_t*)reg0;
    float* xz   = ws;                ws += (size_t)BL * 1536;
    float* xsc  = ws;                ws += (size_t)BL * D_INNER;
    float* dt   = ws;                ws += (size_t)BL * D_INNER;
    float* xdbl = ws;                ws += (size_t)BL * XDBL_LD;
    float* sumdt  = ws;              ws += (size_t)BATCH * NCHUNK * D_INNER;
    float* hstate = ws;              ws += (size_t)BATCH * NCHUNK * D_INNER * D_STATE;
    ushort_t* wbf_in  = (ushort_t*)ws;  ws += (size_t)1536 * D_MODEL / 2;
    ushort_t* wbf_out = (ushort_t*)ws;  ws += (size_t)D_MODEL * D_INNER / 2;

    for (int i = 0; i < 2; i++) {
        const float* hinp = (i == 0) ? x : out;
        cast_bf16_kernel<<<(1536 * D_MODEL + 255) / 256, 256, 0, stream>>>(
            in_proj + (size_t)i * 1536 * D_MODEL, wbf_in, 1536 * D_MODEL);
        cast_bf16_kernel<<<(D_MODEL * D_INNER + 255) / 256, 256, 0, stream>>>(
            out_proj + (size_t)i * D_MODEL * D_INNER, wbf_out, D_MODEL * D_INNER);
        ln_kernel<<<BL, 384, 0, stream>>>(hinp, norm_w + i * D_MODEL,
                                          norm_b + i * D_MODEL, lnb);
        gemm_mfma<<<dim3(BL / 128, 1536 / 128), 256, 0, stream>>>(
            lnb, wbf_in, nullptr, xz, 1536, D_MODEL);
        conv_silu_kernel<<<(BL * D_INNER) / 256, 256, 0, stream>>>(
            xz, conv_w + i * D_INNER * K_CONV, conv_b + i * D_INNER, xsc, i);
        xdbl_gemm<<<BL / 64, 256, 0, stream>>>(
            xsc, x_proj + (size_t)i * 56 * D_INNER, xdbl);
        dt_kernel<<<(BL / DTROWS) * 3, 256, 0, stream>>>(
            xdbl, dt_w + (size_t)i * D_INNER * DT_RANK, dt_b + i * D_INNER, dt);
        scan_pass1<<<BATCH * NCHUNK * 3, 256, 0, stream>>>(
            dt, xsc, xdbl, A_log + (size_t)i * D_INNER * D_STATE,
            hstate, sumdt, i);
        scan_pass2<<<(BATCH * D_INNER * D_STATE) / 256, 256, 0, stream>>>(
            hstate, sumdt, A_log + (size_t)i * D_INNER * D_STATE);
        scan_pass3<<<BATCH * NCHUNK * 3, 256, 0, stream>>>(
            dt, xsc, xz, xdbl, A_log + (size_t)i * D_INNER * D_STATE,
            Dp + i * D_INNER, hstate, ybf, i);
        gemm_mfma<<<dim3(BL / 128, D_MODEL / 128), 256, 0, stream>>>(
            ybf, wbf_out, hinp, out, D_MODEL, D_INNER);
    }
}

// Round 5
// 734.637 us; speedup vs baseline: 5.4884x; 1.0647x over previous
//
#include <hip/hip_runtime.h>
#include <hip/hip_bf16.h>
#include <cstddef>

#define D_MODEL 384
#define D_INNER 768
#define D_STATE 16
#define DT_RANK 24
#define K_CONV  4
#define BATCH   8
#define SEQ     2048
#define BL      (BATCH * SEQ)     // 16384 rows
#define NCHUNK  32
#define LCHUNK  (SEQ / NCHUNK)    // 64
#define XDBL_LD 64                // padded leading dim of x_dbl buffer

typedef unsigned short ushort_t;
typedef __bf16 bf16x8 __attribute__((ext_vector_type(8)));
typedef float  f32x4  __attribute__((ext_vector_type(4)));
typedef unsigned short u16x8 __attribute__((ext_vector_type(8)));

#define GLOBAL_AS(p) ((const __attribute__((address_space(1))) void*)(p))
#define LDS_AS(p)    ((__attribute__((address_space(3))) void*)(p))

__device__ __forceinline__ ushort_t f32_to_bf16_rne(float v) {
    unsigned int u = __float_as_uint(v);
    return (ushort_t)((u + 0x7FFFu + ((u >> 16) & 1u)) >> 16);
}
__device__ __forceinline__ float bf16_to_f32(ushort_t u) {
    return __uint_as_float(((unsigned int)u) << 16);
}

// ---------------------------------------------------------------------------
// Elementwise f32 -> bf16 (RNE) for weights (both directions in one launch).
// ---------------------------------------------------------------------------
__global__ __launch_bounds__(256) void cast_bf16_kernel(
    const float* __restrict__ in, ushort_t* __restrict__ out, int n)
{
    int i = blockIdx.x * 256 + threadIdx.x;
    if (i < n) out[i] = f32_to_bf16_rne(in[i]);
}

// ---------------------------------------------------------------------------
// x_proj cast with zero-padding: (2,56,768) f32 -> (2,64,768) bf16.
// ---------------------------------------------------------------------------
__global__ __launch_bounds__(256) void cast_xproj_kernel(
    const float* __restrict__ in, ushort_t* __restrict__ out)
{
    int i = blockIdx.x * 256 + threadIdx.x;   // 2*64*768
    if (i >= 2 * 64 * D_INNER) return;
    int c   = i % D_INNER;
    int r   = (i / D_INNER) % 64;
    int dir = i / (64 * D_INNER);
    out[i] = (r < 56) ? f32_to_bf16_rne(in[((size_t)dir * 56 + r) * D_INNER + c])
                      : (ushort_t)0;
}

// ---------------------------------------------------------------------------
// LayerNorm over last dim (384), output bf16. One block per row, 384 thr.
// ---------------------------------------------------------------------------
__global__ __launch_bounds__(384) void ln_kernel(
    const float* __restrict__ in, const float* __restrict__ w,
    const float* __restrict__ b, ushort_t* __restrict__ out)
{
    int row = blockIdx.x;
    int tid = threadIdx.x;
    float v = in[(size_t)row * D_MODEL + tid];
    float s = v, sq = v * v;
    #pragma unroll
    for (int o = 32; o; o >>= 1) {
        s  += __shfl_down(s, o);
        sq += __shfl_down(sq, o);
    }
    __shared__ float ss[6], ssq[6];
    __shared__ float mb[2];
    int wid = tid >> 6;
    if ((tid & 63) == 0) { ss[wid] = s; ssq[wid] = sq; }
    __syncthreads();
    if (tid == 0) {
        float S = 0.f, Q = 0.f;
        #pragma unroll
        for (int k = 0; k < 6; k++) { S += ss[k]; Q += ssq[k]; }
        float mu  = S * (1.0f / D_MODEL);
        float var = Q * (1.0f / D_MODEL) - mu * mu;
        mb[0] = mu;
        mb[1] = rsqrtf(var + 1e-5f);
    }
    __syncthreads();
    float r = (v - mb[0]) * mb[1] * w[tid] + b[tid];
    out[(size_t)row * D_MODEL + tid] = f32_to_bf16_rne(r);
}

// ---------------------------------------------------------------------------
// bf16 MFMA GEMM, bf16 output: C = A (MxK) * W^T (W NxK). 128x128 tile,
// BK=32, 4 waves each owning a 64x64 quadrant.
// ---------------------------------------------------------------------------
__global__ __launch_bounds__(256) void gemm_mfma_b16(
    const ushort_t* __restrict__ A, const ushort_t* __restrict__ W,
    ushort_t* __restrict__ C, int N, int K)
{
    __shared__ __bf16 As[128 * 32];
    __shared__ __bf16 Ws[128 * 32];
    int tid  = threadIdx.x;
    int bm = blockIdx.x, bn = blockIdx.y;
    int lane = tid & 63, wave = tid >> 6;
    int wr = wave >> 1, wc = wave & 1;
    int quad = lane >> 4, l16 = lane & 15;

    const ushort_t* Ag = A + (size_t)(bm * 128 + (tid >> 2)) * K + (tid & 3) * 8;
    const ushort_t* Wg = W + (size_t)(bn * 128 + (tid >> 2)) * K + (tid & 3) * 8;

    f32x4 acc[4][4] = {};

    for (int k0 = 0; k0 < K; k0 += 32) {
        __syncthreads();
        __builtin_amdgcn_global_load_lds(GLOBAL_AS(Ag + k0),
                                         LDS_AS(As + tid * 8), 16, 0, 0);
        __builtin_amdgcn_global_load_lds(GLOBAL_AS(Ag + (size_t)64 * K + k0),
                                         LDS_AS(As + 2048 + tid * 8), 16, 0, 0);
        __builtin_amdgcn_global_load_lds(GLOBAL_AS(Wg + k0),
                                         LDS_AS(Ws + tid * 8), 16, 0, 0);
        __builtin_amdgcn_global_load_lds(GLOBAL_AS(Wg + (size_t)64 * K + k0),
                                         LDS_AS(Ws + 2048 + tid * 8), 16, 0, 0);
        __syncthreads();

        bf16x8 af[4], wf[4];
        #pragma unroll
        for (int i = 0; i < 4; i++)
            af[i] = *(const bf16x8*)(As + (wr * 64 + i * 16 + l16) * 32 + quad * 8);
        #pragma unroll
        for (int j = 0; j < 4; j++)
            wf[j] = *(const bf16x8*)(Ws + (wc * 64 + j * 16 + l16) * 32 + quad * 8);
        #pragma unroll
        for (int i = 0; i < 4; i++)
            #pragma unroll
            for (int j = 0; j < 4; j++)
                acc[i][j] = __builtin_amdgcn_mfma_f32_16x16x32_bf16(
                    af[i], wf[j], acc[i][j], 0, 0, 0);
    }

    #pragma unroll
    for (int i = 0; i < 4; i++) {
        #pragma unroll
        for (int r = 0; r < 4; r++) {
            int row = bm * 128 + wr * 64 + i * 16 + quad * 4 + r;
            #pragma unroll
            for (int j = 0; j < 4; j++) {
                int col = bn * 128 + wc * 64 + j * 16 + l16;
                C[(size_t)row * N + col] = f32_to_bf16_rne(acc[i][j][r]);
            }
        }
    }
}

// ---------------------------------------------------------------------------
// bf16 MFMA GEMM, f32 output + f32 residual add (for out_proj).
// ---------------------------------------------------------------------------
__global__ __launch_bounds__(256) void gemm_mfma_f32(
    const ushort_t* __restrict__ A, const ushort_t* __restrict__ W,
    const float* __restrict__ resid, float* __restrict__ C, int N, int K)
{
    __shared__ __bf16 As[128 * 32];
    __shared__ __bf16 Ws[128 * 32];
    int tid  = threadIdx.x;
    int bm = blockIdx.x, bn = blockIdx.y;
    int lane = tid & 63, wave = tid >> 6;
    int wr = wave >> 1, wc = wave & 1;
    int quad = lane >> 4, l16 = lane & 15;

    const ushort_t* Ag = A + (size_t)(bm * 128 + (tid >> 2)) * K + (tid & 3) * 8;
    const ushort_t* Wg = W + (size_t)(bn * 128 + (tid >> 2)) * K + (tid & 3) * 8;

    f32x4 acc[4][4] = {};

    for (int k0 = 0; k0 < K; k0 += 32) {
        __syncthreads();
        __builtin_amdgcn_global_load_lds(GLOBAL_AS(Ag + k0),
                                         LDS_AS(As + tid * 8), 16, 0, 0);
        __builtin_amdgcn_global_load_lds(GLOBAL_AS(Ag + (size_t)64 * K + k0),
                                         LDS_AS(As + 2048 + tid * 8), 16, 0, 0);
        __builtin_amdgcn_global_load_lds(GLOBAL_AS(Wg + k0),
                                         LDS_AS(Ws + tid * 8), 16, 0, 0);
        __builtin_amdgcn_global_load_lds(GLOBAL_AS(Wg + (size_t)64 * K + k0),
                                         LDS_AS(Ws + 2048 + tid * 8), 16, 0, 0);
        __syncthreads();

        bf16x8 af[4], wf[4];
        #pragma unroll
        for (int i = 0; i < 4; i++)
            af[i] = *(const bf16x8*)(As + (wr * 64 + i * 16 + l16) * 32 + quad * 8);
        #pragma unroll
        for (int j = 0; j < 4; j++)
            wf[j] = *(const bf16x8*)(Ws + (wc * 64 + j * 16 + l16) * 32 + quad * 8);
        #pragma unroll
        for (int i = 0; i < 4; i++)
            #pragma unroll
            for (int j = 0; j < 4; j++)
                acc[i][j] = __builtin_amdgcn_mfma_f32_16x16x32_bf16(
                    af[i], wf[j], acc[i][j], 0, 0, 0);
    }

    #pragma unroll
    for (int i = 0; i < 4; i++) {
        #pragma unroll
        for (int r = 0; r < 4; r++) {
            int row = bm * 128 + wr * 64 + i * 16 + quad * 4 + r;
            #pragma unroll
            for (int j = 0; j < 4; j++) {
                int col = bn * 128 + wc * 64 + j * 16 + l16;
                size_t idx = (size_t)row * N + col;
                C[idx] = acc[i][j][r] + resid[idx];
            }
        }
    }
}

// ---------------------------------------------------------------------------
// x_dbl = xs(bf16) @ x_proj^T(bf16, 64x768 zero-padded), f32 out (BLx64).
// 128-row tile, 4 waves x (32 rows x 64 cols) = 8 MFMAs per K-step.
// ---------------------------------------------------------------------------
__global__ __launch_bounds__(256) void xdbl_mfma(
    const ushort_t* __restrict__ A, const ushort_t* __restrict__ W,
    float* __restrict__ C)
{
    __shared__ __bf16 As[128 * 32];
    __shared__ __bf16 Ws[64 * 32];
    int tid  = threadIdx.x;
    int bm = blockIdx.x;
    int lane = tid & 63, wave = tid >> 6;
    int quad = lane >> 4, l16 = lane & 15;

    const ushort_t* Ag = A + (size_t)(bm * 128 + (tid >> 2)) * D_INNER + (tid & 3) * 8;
    const ushort_t* Wg = W + (size_t)(tid >> 2) * D_INNER + (tid & 3) * 8;

    f32x4 acc[2][4] = {};

    for (int k0 = 0; k0 < D_INNER; k0 += 32) {
        __syncthreads();
        __builtin_amdgcn_global_load_lds(GLOBAL_AS(Ag + k0),
                                         LDS_AS(As + tid * 8), 16, 0, 0);
        __builtin_amdgcn_global_load_lds(GLOBAL_AS(Ag + (size_t)64 * D_INNER + k0),
                                         LDS_AS(As + 2048 + tid * 8), 16, 0, 0);
        __builtin_amdgcn_global_load_lds(GLOBAL_AS(Wg + k0),
                                         LDS_AS(Ws + tid * 8), 16, 0, 0);
        __syncthreads();

        bf16x8 af[2], wf[4];
        #pragma unroll
        for (int i = 0; i < 2; i++)
            af[i] = *(const bf16x8*)(As + (wave * 32 + i * 16 + l16) * 32 + quad * 8);
        #pragma unroll
        for (int j = 0; j < 4; j++)
            wf[j] = *(const bf16x8*)(Ws + (j * 16 + l16) * 32 + quad * 8);
        #pragma unroll
        for (int i = 0; i < 2; i++)
            #pragma unroll
            for (int j = 0; j < 4; j++)
                acc[i][j] = __builtin_amdgcn_mfma_f32_16x16x32_bf16(
                    af[i], wf[j], acc[i][j], 0, 0, 0);
    }

    #pragma unroll
    for (int i = 0; i < 2; i++) {
        #pragma unroll
        for (int r = 0; r < 4; r++) {
            int row = bm * 128 + wave * 32 + i * 16 + quad * 4 + r;
            #pragma unroll
            for (int j = 0; j < 4; j++) {
                int col = j * 16 + l16;
                C[(size_t)row * XDBL_LD + col] = acc[i][j][r];
            }
        }
    }
}

// ---------------------------------------------------------------------------
// Causal depthwise conv (k=4) + bias + SiLU, bf16 in/out, 8 ch per thread.
// ---------------------------------------------------------------------------
__global__ __launch_bounds__(256) void conv_silu_kernel(
    const ushort_t* __restrict__ xz, const float* __restrict__ cw,
    const float* __restrict__ cb, ushort_t* __restrict__ xsc, int dir)
{
    int idx8 = blockIdx.x * 256 + threadIdx.x;   // BL * 96
    int c8   = (idx8 % 96) * 8;
    int row  = idx8 / 96;
    int l    = row % SEQ;
    int b0   = row - l;

    float acc[8];
    #pragma unroll
    for (int j = 0; j < 8; j++) acc[j] = cb[c8 + j];

    #pragma unroll
    for (int k = 0; k < 4; k++) {
        int ls = dir ? (l + k) : (l - 3 + k);
        int wk = dir ? (3 - k) : k;
        bool ok = dir ? (ls < SEQ) : (ls >= 0);
        if (ok) {
            u16x8 v = *(const u16x8*)(xz + (size_t)(b0 + ls) * 1536 + c8);
            #pragma unroll
            for (int j = 0; j < 8; j++)
                acc[j] = fmaf(bf16_to_f32(v[j]), cw[(c8 + j) * 4 + wk], acc[j]);
        }
    }
    u16x8 o;
    #pragma unroll
    for (int j = 0; j < 8; j++) {
        float sg = 1.0f / (1.0f + __expf(-acc[j]));
        o[j] = f32_to_bf16_rne(acc[j] * sg);
    }
    *(u16x8*)(xsc + (size_t)row * D_INNER + c8) = o;
}

// ---------------------------------------------------------------------------
// Chunked selective scan, pass 1: per-chunk local scan from h=0.
// dt computed inline: softplus(xdbl[row][0:24] . w[d] + bias[d]).
// ---------------------------------------------------------------------------
__global__ __launch_bounds__(256) void scan_pass1(
    const ushort_t* __restrict__ xsc, const float* __restrict__ xdbl,
    const float* __restrict__ dtw, const float* __restrict__ dtbias,
    const float* __restrict__ A_log,
    float* __restrict__ hstate, float* __restrict__ sumdt_buf, int dir)
{
    int g = blockIdx.x % 3;
    int c = (blockIdx.x / 3) % NCHUNK;
    int b = blockIdx.x / (3 * NCHUNK);
    int d = g * 256 + threadIdx.x;
    float A[D_STATE], w[DT_RANK];
    #pragma unroll
    for (int n = 0; n < D_STATE; n++) A[n] = -__expf(A_log[d * D_STATE + n]);
    #pragma unroll
    for (int r = 0; r < DT_RANK; r++) w[r] = dtw[d * DT_RANK + r];
    float bias = dtbias[d];
    float h[D_STATE] = {};
    float sdt = 0.f;
    size_t base = (size_t)b * SEQ;
    for (int i = 0; i < LCHUNK; i++) {
        int p = c * LCHUNK + i;
        int l = dir ? (SEQ - 1 - p) : p;
        size_t row = base + l;
        const float* xr = xdbl + row * XDBL_LD;
        float acc = bias;
        #pragma unroll
        for (int r = 0; r < DT_RANK; r++) acc = fmaf(xr[r], w[r], acc);
        float dtv = acc > 20.f ? acc : __logf(1.f + __expf(acc));
        float xv  = bf16_to_f32(xsc[row * D_INNER + d]);
        float dtx = dtv * xv;
        sdt += dtv;
        const float* Br = xr + DT_RANK;
        #pragma unroll
        for (int n = 0; n < D_STATE; n++)
            h[n] = fmaf(__expf(dtv * A[n]), h[n], dtx * Br[n]);
    }
    size_t cidx = (size_t)(b * NCHUNK + c) * D_INNER + d;
    sumdt_buf[cidx] = sdt;
    #pragma unroll
    for (int n = 0; n < D_STATE; n++) hstate[cidx * D_STATE + n] = h[n];
}

// ---------------------------------------------------------------------------
// Pass 2: in-place combine; hstate[c] becomes the ENTRY state of chunk c.
// ---------------------------------------------------------------------------
__global__ __launch_bounds__(256) void scan_pass2(
    float* __restrict__ hstate, const float* __restrict__ sumdt_buf,
    const float* __restrict__ A_log)
{
    int gid = blockIdx.x * 256 + threadIdx.x;   // BATCH * D_INNER * 16
    int n = gid & 15;
    int d = (gid >> 4) % D_INNER;
    int b = gid / (16 * D_INNER);
    float A = -__expf(A_log[d * D_STATE + n]);
    float h = 0.f;
    for (int c = 0; c < NCHUNK; c++) {
        size_t cidx = (size_t)(b * NCHUNK + c) * D_INNER + d;
        float ho = hstate[cidx * D_STATE + n];
        hstate[cidx * D_STATE + n] = h;
        h = fmaf(__expf(A * sumdt_buf[cidx]), h, ho);
    }
}

// ---------------------------------------------------------------------------
// Pass 3: local scan seeded with entry state; dt inline; fuses y = h.C + D*x
// and SiLU(z) gating; emits y bf16.
// ---------------------------------------------------------------------------
__global__ __launch_bounds__(256) void scan_pass3(
    const ushort_t* __restrict__ xsc, const ushort_t* __restrict__ xz,
    const float* __restrict__ xdbl, const float* __restrict__ dtw,
    const float* __restrict__ dtbias, const float* __restrict__ A_log,
    const float* __restrict__ Dp, const float* __restrict__ hstate,
    ushort_t* __restrict__ y, int dir)
{
    int g = blockIdx.x % 3;
    int c = (blockIdx.x / 3) % NCHUNK;
    int b = blockIdx.x / (3 * NCHUNK);
    int d = g * 256 + threadIdx.x;
    size_t cidx = (size_t)(b * NCHUNK + c) * D_INNER + d;
    float A[D_STATE], h[D_STATE], w[DT_RANK];
    #pragma unroll
    for (int n = 0; n < D_STATE; n++) {
        A[n] = -__expf(A_log[d * D_STATE + n]);
        h[n] = hstate[cidx * D_STATE + n];
    }
    #pragma unroll
    for (int r = 0; r < DT_RANK; r++) w[r] = dtw[d * DT_RANK + r];
    float bias = dtbias[d];
    float Dd = Dp[d];
    size_t base = (size_t)b * SEQ;
    for (int i = 0; i < LCHUNK; i++) {
        int p = c * LCHUNK + i;
        int l = dir ? (SEQ - 1 - p) : p;
        size_t row = base + l;
        const float* xr = xdbl + row * XDBL_LD;
        float acc = bias;
        #pragma unroll
        for (int r = 0; r < DT_RANK; r++) acc = fmaf(xr[r], w[r], acc);
        float dtv = acc > 20.f ? acc : __logf(1.f + __expf(acc));
        float xv  = bf16_to_f32(xsc[row * D_INNER + d]);
        float zv  = bf16_to_f32(xz[row * 1536 + D_INNER + d]);
        float dtx = dtv * xv;
        const float* Br = xr + DT_RANK;
        const float* Cr = xr + DT_RANK + D_STATE;
        float yv = 0.f;
        #pragma unroll
        for (int n = 0; n < D_STATE; n++) {
            h[n] = fmaf(__expf(dtv * A[n]), h[n], dtx * Br[n]);
            yv = fmaf(h[n], Cr[n], yv);
        }
        yv = fmaf(xv, Dd, yv);
        float sg = 1.f / (1.f + __expf(-zv));
        yv *= zv * sg;
        y[row * D_INNER + d] = f32_to_bf16_rne(yv);
    }
}

// ---------------------------------------------------------------------------
extern "C" void kernel_launch(void* const* d_in, const int* in_sizes, int n_in,
                              void* d_out, int out_size, void* d_ws, size_t ws_size,
                              hipStream_t stream)
{
    const float* x       = (const float*)d_in[0];
    const float* norm_w  = (const float*)d_in[1];
    const float* norm_b  = (const float*)d_in[2];
    const float* in_proj = (const float*)d_in[3];
    const float* conv_w  = (const float*)d_in[4];
    const float* conv_b  = (const float*)d_in[5];
    const float* x_proj  = (const float*)d_in[6];
    const float* dt_w    = (const float*)d_in[7];
    const float* dt_b    = (const float*)d_in[8];
    const float* A_log   = (const float*)d_in[9];
    const float* Dp      = (const float*)d_in[10];
    const float* out_proj= (const float*)d_in[11];
    float* out = (float*)d_out;

    float* ws   = (float*)d_ws;
    // lnb (bf16 BL*384) and ybf (bf16 BL*768) share one region.
    float* reg0 = ws;                ws += (size_t)BL * D_INNER / 2;
    ushort_t* lnb = (ushort_t*)reg0;
    ushort_t* ybf = (ushort_t*)reg0;
    ushort_t* xzb  = (ushort_t*)ws;  ws += (size_t)BL * 1536 / 2;
    ushort_t* xscb = (ushort_t*)ws;  ws += (size_t)BL * D_INNER / 2;
    float* xdbl = ws;                ws += (size_t)BL * XDBL_LD;
    float* sumdt  = ws;              ws += (size_t)BATCH * NCHUNK * D_INNER;
    float* hstate = ws;              ws += (size_t)BATCH * NCHUNK * D_INNER * D_STATE;
    ushort_t* wbf_in  = (ushort_t*)ws;  ws += (size_t)2 * 1536 * D_MODEL / 2;
    ushort_t* wbf_out = (ushort_t*)ws;  ws += (size_t)2 * D_MODEL * D_INNER / 2;
    ushort_t* xp_bf   = (ushort_t*)ws;  ws += (size_t)2 * 64 * D_INNER / 2;

    // weight casts, both directions, once
    cast_bf16_kernel<<<(2 * 1536 * D_MODEL + 255) / 256, 256, 0, stream>>>(
        in_proj, wbf_in, 2 * 1536 * D_MODEL);
    cast_bf16_kernel<<<(2 * D_MODEL * D_INNER + 255) / 256, 256, 0, stream>>>(
        out_proj, wbf_out, 2 * D_MODEL * D_INNER);
    cast_xproj_kernel<<<(2 * 64 * D_INNER + 255) / 256, 256, 0, stream>>>(
        x_proj, xp_bf);

    for (int i = 0; i < 2; i++) {
        const float* hinp = (i == 0) ? x : out;
        ln_kernel<<<BL, 384, 0, stream>>>(hinp, norm_w + i * D_MODEL,
                                          norm_b + i * D_MODEL, lnb);
        gemm_mfma_b16<<<dim3(BL / 128, 1536 / 128), 256, 0, stream>>>(
            lnb, wbf_in + (size_t)i * 1536 * D_MODEL, xzb, 1536, D_MODEL);
        conv_silu_kernel<<<(BL * 96) / 256, 256, 0, stream>>>(
            xzb, conv_w + i * D_INNER * K_CONV, conv_b + i * D_INNER, xscb, i);
        xdbl_mfma<<<BL / 128, 256, 0, stream>>>(
            xscb, xp_bf + (size_t)i * 64 * D_INNER, xdbl);
        scan_pass1<<<BATCH * NCHUNK * 3, 256, 0, stream>>>(
            xscb, xdbl, dt_w + (size_t)i * D_INNER * DT_RANK,
            dt_b + i * D_INNER, A_log + (size_t)i * D_INNER * D_STATE,
            hstate, sumdt, i);
        scan_pass2<<<(BATCH * D_INNER * D_STATE) / 256, 256, 0, stream>>>(
            hstate, sumdt, A_log + (size_t)i * D_INNER * D_STATE);
        scan_pass3<<<BATCH * NCHUNK * 3, 256, 0, stream>>>(
            xscb, xzb, xdbl, dt_w + (size_t)i * D_INNER * DT_RANK,
            dt_b + i * D_INNER, A_log + (size_t)i * D_INNER * D_STATE,
            Dp + i * D_INNER, hstate, ybf, i);
        gemm_mfma_f32<<<dim3(BL / 128, D_MODEL / 128), 256, 0, stream>>>(
            ybf, wbf_out + (size_t)i * D_MODEL * D_INNER, hinp, out,
            D_MODEL, D_INNER);
    }
}

// Round 6
// 593.955 us; speedup vs baseline: 6.7884x; 1.2369x over previous
//
#include <hip/hip_runtime.h>
#include <hip/hip_bf16.h>
#include <cstddef>

#define D_MODEL 384
#define D_INNER 768
#define D_STATE 16
#define DT_RANK 24
#define K_CONV  4
#define BATCH   8
#define SEQ     2048
#define BL      (BATCH * SEQ)     // 16384 rows
#define NCHUNK  32
#define LCHUNK  (SEQ / NCHUNK)    // 64
#define XDBL_LD 64                // padded leading dim of x_dbl buffer

typedef unsigned short ushort_t;
typedef __bf16 bf16x8 __attribute__((ext_vector_type(8)));
typedef float  f32x4  __attribute__((ext_vector_type(4)));
typedef unsigned short u16x8 __attribute__((ext_vector_type(8)));

#define GLOBAL_AS(p) ((const __attribute__((address_space(1))) void*)(p))
#define LDS_AS(p)    ((__attribute__((address_space(3))) void*)(p))

__device__ __forceinline__ ushort_t f32_to_bf16_rne(float v) {
    unsigned int u = __float_as_uint(v);
    return (ushort_t)((u + 0x7FFFu + ((u >> 16) & 1u)) >> 16);
}
__device__ __forceinline__ float bf16_to_f32(ushort_t u) {
    return __uint_as_float(((unsigned int)u) << 16);
}

// ---------------------------------------------------------------------------
// Elementwise f32 -> bf16 (RNE) for weights (both directions in one launch).
// ---------------------------------------------------------------------------
__global__ __launch_bounds__(256) void cast_bf16_kernel(
    const float* __restrict__ in, ushort_t* __restrict__ out, int n)
{
    int i = blockIdx.x * 256 + threadIdx.x;
    if (i < n) out[i] = f32_to_bf16_rne(in[i]);
}

// ---------------------------------------------------------------------------
// x_proj cast with zero-padding: (2,56,768) f32 -> (2,64,768) bf16.
// ---------------------------------------------------------------------------
__global__ __launch_bounds__(256) void cast_xproj_kernel(
    const float* __restrict__ in, ushort_t* __restrict__ out)
{
    int i = blockIdx.x * 256 + threadIdx.x;   // 2*64*768
    if (i >= 2 * 64 * D_INNER) return;
    int c   = i % D_INNER;
    int r   = (i / D_INNER) % 64;
    int dir = i / (64 * D_INNER);
    out[i] = (r < 56) ? f32_to_bf16_rne(in[((size_t)dir * 56 + r) * D_INNER + c])
                      : (ushort_t)0;
}

// ---------------------------------------------------------------------------
// Transpose small per-channel params to channel-contiguous layouts:
//   cwt[dir][k][768]  <- conv_w[dir][c][k]      (6144 elems)
//   alt[dir][n][768]  <- A_log[dir][d][n]       (24576 elems)
//   dwt[dir][r][768]  <- dt_w[dir][d][r]        (36864 elems)
// ---------------------------------------------------------------------------
__global__ __launch_bounds__(256) void prep_transpose_kernel(
    const float* __restrict__ conv_w, const float* __restrict__ A_log,
    const float* __restrict__ dt_w, float* __restrict__ cwt,
    float* __restrict__ alt, float* __restrict__ dwt)
{
    int i = blockIdx.x * 256 + threadIdx.x;
    const int NCW = 2 * K_CONV * D_INNER;          // 6144
    const int NAL = 2 * D_STATE * D_INNER;         // 24576
    const int NDW = 2 * DT_RANK * D_INNER;         // 36864
    if (i < NCW) {
        int c = i % D_INNER, k = (i / D_INNER) % K_CONV, dir = i / (K_CONV * D_INNER);
        cwt[i] = conv_w[((size_t)dir * D_INNER + c) * K_CONV + k];
    } else if (i < NCW + NAL) {
        int j = i - NCW;
        int d = j % D_INNER, n = (j / D_INNER) % D_STATE, dir = j / (D_STATE * D_INNER);
        alt[j] = A_log[((size_t)dir * D_INNER + d) * D_STATE + n];
    } else if (i < NCW + NAL + NDW) {
        int j = i - NCW - NAL;
        int d = j % D_INNER, r = (j / D_INNER) % DT_RANK, dir = j / (DT_RANK * D_INNER);
        dwt[j] = dt_w[((size_t)dir * D_INNER + d) * DT_RANK + r];
    }
}

// ---------------------------------------------------------------------------
// LayerNorm over last dim (384), output bf16. One block per row, 384 thr.
// ---------------------------------------------------------------------------
__global__ __launch_bounds__(384) void ln_kernel(
    const float* __restrict__ in, const float* __restrict__ w,
    const float* __restrict__ b, ushort_t* __restrict__ out)
{
    int row = blockIdx.x;
    int tid = threadIdx.x;
    float v = in[(size_t)row * D_MODEL + tid];
    float s = v, sq = v * v;
    #pragma unroll
    for (int o = 32; o; o >>= 1) {
        s  += __shfl_down(s, o);
        sq += __shfl_down(sq, o);
    }
    __shared__ float ss[6], ssq[6];
    __shared__ float mb[2];
    int wid = tid >> 6;
    if ((tid & 63) == 0) { ss[wid] = s; ssq[wid] = sq; }
    __syncthreads();
    if (tid == 0) {
        float S = 0.f, Q = 0.f;
        #pragma unroll
        for (int k = 0; k < 6; k++) { S += ss[k]; Q += ssq[k]; }
        float mu  = S * (1.0f / D_MODEL);
        float var = Q * (1.0f / D_MODEL) - mu * mu;
        mb[0] = mu;
        mb[1] = rsqrtf(var + 1e-5f);
    }
    __syncthreads();
    float r = (v - mb[0]) * mb[1] * w[tid] + b[tid];
    out[(size_t)row * D_MODEL + tid] = f32_to_bf16_rne(r);
}

// ---------------------------------------------------------------------------
// bf16 MFMA GEMM, bf16 output: C = A (MxK) * W^T (W NxK). 128x128 tile,
// BK=32, 4 waves each owning a 64x64 quadrant.
// ---------------------------------------------------------------------------
__global__ __launch_bounds__(256) void gemm_mfma_b16(
    const ushort_t* __restrict__ A, const ushort_t* __restrict__ W,
    ushort_t* __restrict__ C, int N, int K)
{
    __shared__ __bf16 As[128 * 32];
    __shared__ __bf16 Ws[128 * 32];
    int tid  = threadIdx.x;
    int bm = blockIdx.x, bn = blockIdx.y;
    int lane = tid & 63, wave = tid >> 6;
    int wr = wave >> 1, wc = wave & 1;
    int quad = lane >> 4, l16 = lane & 15;

    const ushort_t* Ag = A + (size_t)(bm * 128 + (tid >> 2)) * K + (tid & 3) * 8;
    const ushort_t* Wg = W + (size_t)(bn * 128 + (tid >> 2)) * K + (tid & 3) * 8;

    f32x4 acc[4][4] = {};

    for (int k0 = 0; k0 < K; k0 += 32) {
        __syncthreads();
        __builtin_amdgcn_global_load_lds(GLOBAL_AS(Ag + k0),
                                         LDS_AS(As + tid * 8), 16, 0, 0);
        __builtin_amdgcn_global_load_lds(GLOBAL_AS(Ag + (size_t)64 * K + k0),
                                         LDS_AS(As + 2048 + tid * 8), 16, 0, 0);
        __builtin_amdgcn_global_load_lds(GLOBAL_AS(Wg + k0),
                                         LDS_AS(Ws + tid * 8), 16, 0, 0);
        __builtin_amdgcn_global_load_lds(GLOBAL_AS(Wg + (size_t)64 * K + k0),
                                         LDS_AS(Ws + 2048 + tid * 8), 16, 0, 0);
        __syncthreads();

        bf16x8 af[4], wf[4];
        #pragma unroll
        for (int i = 0; i < 4; i++)
            af[i] = *(const bf16x8*)(As + (wr * 64 + i * 16 + l16) * 32 + quad * 8);
        #pragma unroll
        for (int j = 0; j < 4; j++)
            wf[j] = *(const bf16x8*)(Ws + (wc * 64 + j * 16 + l16) * 32 + quad * 8);
        #pragma unroll
        for (int i = 0; i < 4; i++)
            #pragma unroll
            for (int j = 0; j < 4; j++)
                acc[i][j] = __builtin_amdgcn_mfma_f32_16x16x32_bf16(
                    af[i], wf[j], acc[i][j], 0, 0, 0);
    }

    #pragma unroll
    for (int i = 0; i < 4; i++) {
        #pragma unroll
        for (int r = 0; r < 4; r++) {
            int row = bm * 128 + wr * 64 + i * 16 + quad * 4 + r;
            #pragma unroll
            for (int j = 0; j < 4; j++) {
                int col = bn * 128 + wc * 64 + j * 16 + l16;
                C[(size_t)row * N + col] = f32_to_bf16_rne(acc[i][j][r]);
            }
        }
    }
}

// ---------------------------------------------------------------------------
// bf16 MFMA GEMM, f32 output + f32 residual add (for out_proj).
// ---------------------------------------------------------------------------
__global__ __launch_bounds__(256) void gemm_mfma_f32(
    const ushort_t* __restrict__ A, const ushort_t* __restrict__ W,
    const float* __restrict__ resid, float* __restrict__ C, int N, int K)
{
    __shared__ __bf16 As[128 * 32];
    __shared__ __bf16 Ws[128 * 32];
    int tid  = threadIdx.x;
    int bm = blockIdx.x, bn = blockIdx.y;
    int lane = tid & 63, wave = tid >> 6;
    int wr = wave >> 1, wc = wave & 1;
    int quad = lane >> 4, l16 = lane & 15;

    const ushort_t* Ag = A + (size_t)(bm * 128 + (tid >> 2)) * K + (tid & 3) * 8;
    const ushort_t* Wg = W + (size_t)(bn * 128 + (tid >> 2)) * K + (tid & 3) * 8;

    f32x4 acc[4][4] = {};

    for (int k0 = 0; k0 < K; k0 += 32) {
        __syncthreads();
        __builtin_amdgcn_global_load_lds(GLOBAL_AS(Ag + k0),
                                         LDS_AS(As + tid * 8), 16, 0, 0);
        __builtin_amdgcn_global_load_lds(GLOBAL_AS(Ag + (size_t)64 * K + k0),
                                         LDS_AS(As + 2048 + tid * 8), 16, 0, 0);
        __builtin_amdgcn_global_load_lds(GLOBAL_AS(Wg + k0),
                                         LDS_AS(Ws + tid * 8), 16, 0, 0);
        __builtin_amdgcn_global_load_lds(GLOBAL_AS(Wg + (size_t)64 * K + k0),
                                         LDS_AS(Ws + 2048 + tid * 8), 16, 0, 0);
        __syncthreads();

        bf16x8 af[4], wf[4];
        #pragma unroll
        for (int i = 0; i < 4; i++)
            af[i] = *(const bf16x8*)(As + (wr * 64 + i * 16 + l16) * 32 + quad * 8);
        #pragma unroll
        for (int j = 0; j < 4; j++)
            wf[j] = *(const bf16x8*)(Ws + (wc * 64 + j * 16 + l16) * 32 + quad * 8);
        #pragma unroll
        for (int i = 0; i < 4; i++)
            #pragma unroll
            for (int j = 0; j < 4; j++)
                acc[i][j] = __builtin_amdgcn_mfma_f32_16x16x32_bf16(
                    af[i], wf[j], acc[i][j], 0, 0, 0);
    }

    #pragma unroll
    for (int i = 0; i < 4; i++) {
        #pragma unroll
        for (int r = 0; r < 4; r++) {
            int row = bm * 128 + wr * 64 + i * 16 + quad * 4 + r;
            #pragma unroll
            for (int j = 0; j < 4; j++) {
                int col = bn * 128 + wc * 64 + j * 16 + l16;
                size_t idx = (size_t)row * N + col;
                C[idx] = acc[i][j][r] + resid[idx];
            }
        }
    }
}

// ---------------------------------------------------------------------------
// x_dbl = xs(bf16) @ x_proj^T(bf16, 64x768 zero-padded), f32 out (BLx64).
// ---------------------------------------------------------------------------
__global__ __launch_bounds__(256) void xdbl_mfma(
    const ushort_t* __restrict__ A, const ushort_t* __restrict__ W,
    float* __restrict__ C)
{
    __shared__ __bf16 As[128 * 32];
    __shared__ __bf16 Ws[64 * 32];
    int tid  = threadIdx.x;
    int bm = blockIdx.x;
    int lane = tid & 63, wave = tid >> 6;
    int quad = lane >> 4, l16 = lane & 15;

    const ushort_t* Ag = A + (size_t)(bm * 128 + (tid >> 2)) * D_INNER + (tid & 3) * 8;
    const ushort_t* Wg = W + (size_t)(tid >> 2) * D_INNER + (tid & 3) * 8;

    f32x4 acc[2][4] = {};

    for (int k0 = 0; k0 < D_INNER; k0 += 32) {
        __syncthreads();
        __builtin_amdgcn_global_load_lds(GLOBAL_AS(Ag + k0),
                                         LDS_AS(As + tid * 8), 16, 0, 0);
        __builtin_amdgcn_global_load_lds(GLOBAL_AS(Ag + (size_t)64 * D_INNER + k0),
                                         LDS_AS(As + 2048 + tid * 8), 16, 0, 0);
        __builtin_amdgcn_global_load_lds(GLOBAL_AS(Wg + k0),
                                         LDS_AS(Ws + tid * 8), 16, 0, 0);
        __syncthreads();

        bf16x8 af[2], wf[4];
        #pragma unroll
        for (int i = 0; i < 2; i++)
            af[i] = *(const bf16x8*)(As + (wave * 32 + i * 16 + l16) * 32 + quad * 8);
        #pragma unroll
        for (int j = 0; j < 4; j++)
            wf[j] = *(const bf16x8*)(Ws + (j * 16 + l16) * 32 + quad * 8);
        #pragma unroll
        for (int i = 0; i < 2; i++)
            #pragma unroll
            for (int j = 0; j < 4; j++)
                acc[i][j] = __builtin_amdgcn_mfma_f32_16x16x32_bf16(
                    af[i], wf[j], acc[i][j], 0, 0, 0);
    }

    #pragma unroll
    for (int i = 0; i < 2; i++) {
        #pragma unroll
        for (int r = 0; r < 4; r++) {
            int row = bm * 128 + wave * 32 + i * 16 + quad * 4 + r;
            #pragma unroll
            for (int j = 0; j < 4; j++) {
                int col = j * 16 + l16;
                C[(size_t)row * XDBL_LD + col] = acc[i][j][r];
            }
        }
    }
}

// ---------------------------------------------------------------------------
// Causal depthwise conv (k=4) + bias + SiLU, bf16 in/out, 8 ch per thread.
// Weights from transposed cwt[k][768] -> float4 loads (32 B lane stride).
// ---------------------------------------------------------------------------
__global__ __launch_bounds__(256) void conv_silu_kernel(
    const ushort_t* __restrict__ xz, const float* __restrict__ cwt,
    const float* __restrict__ cb, ushort_t* __restrict__ xsc, int dir)
{
    int idx8 = blockIdx.x * 256 + threadIdx.x;   // BL * 96
    int c8   = (idx8 % 96) * 8;
    int row  = idx8 / 96;
    int l    = row % SEQ;
    int b0   = row - l;

    float acc[8];
    float4 bv0 = *(const float4*)(cb + c8);
    float4 bv1 = *(const float4*)(cb + c8 + 4);
    acc[0] = bv0.x; acc[1] = bv0.y; acc[2] = bv0.z; acc[3] = bv0.w;
    acc[4] = bv1.x; acc[5] = bv1.y; acc[6] = bv1.z; acc[7] = bv1.w;

    #pragma unroll
    for (int k = 0; k < 4; k++) {
        int ls = dir ? (l + k) : (l - 3 + k);
        int wk = dir ? (3 - k) : k;
        bool ok = dir ? (ls < SEQ) : (ls >= 0);
        if (ok) {
            u16x8 v = *(const u16x8*)(xz + (size_t)(b0 + ls) * 1536 + c8);
            float4 w0 = *(const float4*)(cwt + wk * D_INNER + c8);
            float4 w1 = *(const float4*)(cwt + wk * D_INNER + c8 + 4);
            float wv[8] = {w0.x, w0.y, w0.z, w0.w, w1.x, w1.y, w1.z, w1.w};
            #pragma unroll
            for (int j = 0; j < 8; j++)
                acc[j] = fmaf(bf16_to_f32(v[j]), wv[j], acc[j]);
        }
    }
    u16x8 o;
    #pragma unroll
    for (int j = 0; j < 8; j++) {
        float sg = 1.0f / (1.0f + __expf(-acc[j]));
        o[j] = f32_to_bf16_rne(acc[j] * sg);
    }
    *(u16x8*)(xsc + (size_t)row * D_INNER + c8) = o;
}

// ---------------------------------------------------------------------------
// Chunked selective scan, pass 1: per-chunk local scan from h=0.
// dt inline; A_log/dt_w from transposed (lane-contiguous) layouts.
// ---------------------------------------------------------------------------
__global__ __launch_bounds__(256) void scan_pass1(
    const ushort_t* __restrict__ xsc, const float* __restrict__ xdbl,
    const float* __restrict__ dwt, const float* __restrict__ dtbias,
    const float* __restrict__ alt,
    float* __restrict__ hstate, float* __restrict__ sumdt_buf, int dir)
{
    int g = blockIdx.x % 3;
    int c = (blockIdx.x / 3) % NCHUNK;
    int b = blockIdx.x / (3 * NCHUNK);
    int d = g * 256 + threadIdx.x;
    float A[D_STATE], w[DT_RANK];
    #pragma unroll
    for (int n = 0; n < D_STATE; n++) A[n] = -__expf(alt[n * D_INNER + d]);
    #pragma unroll
    for (int r = 0; r < DT_RANK; r++) w[r] = dwt[r * D_INNER + d];
    float bias = dtbias[d];
    float h[D_STATE] = {};
    float sdt = 0.f;
    size_t base = (size_t)b * SEQ;
    for (int i = 0; i < LCHUNK; i++) {
        int p = c * LCHUNK + i;
        int l = dir ? (SEQ - 1 - p) : p;
        size_t row = base + l;
        const float* xr = xdbl + row * XDBL_LD;
        float acc = bias;
        #pragma unroll
        for (int r = 0; r < DT_RANK; r++) acc = fmaf(xr[r], w[r], acc);
        float dtv = acc > 20.f ? acc : __logf(1.f + __expf(acc));
        float xv  = bf16_to_f32(xsc[row * D_INNER + d]);
        float dtx = dtv * xv;
        sdt += dtv;
        const float* Br = xr + DT_RANK;
        #pragma unroll
        for (int n = 0; n < D_STATE; n++)
            h[n] = fmaf(__expf(dtv * A[n]), h[n], dtx * Br[n]);
    }
    size_t cidx = (size_t)(b * NCHUNK + c) * D_INNER + d;
    sumdt_buf[cidx] = sdt;
    #pragma unroll
    for (int n = 0; n < D_STATE; n++) hstate[cidx * D_STATE + n] = h[n];
}

// ---------------------------------------------------------------------------
// Pass 2: in-place combine; hstate[c] becomes the ENTRY state of chunk c.
// ---------------------------------------------------------------------------
__global__ __launch_bounds__(256) void scan_pass2(
    float* __restrict__ hstate, const float* __restrict__ sumdt_buf,
    const float* __restrict__ alt)
{
    int gid = blockIdx.x * 256 + threadIdx.x;   // BATCH * D_INNER * 16
    int n = gid & 15;
    int d = (gid >> 4) % D_INNER;
    int b = gid / (16 * D_INNER);
    float A = -__expf(alt[n * D_INNER + d]);
    float h = 0.f;
    for (int c = 0; c < NCHUNK; c++) {
        size_t cidx = (size_t)(b * NCHUNK + c) * D_INNER + d;
        float ho = hstate[cidx * D_STATE + n];
        hstate[cidx * D_STATE + n] = h;
        h = fmaf(__expf(A * sumdt_buf[cidx]), h, ho);
    }
}

// ---------------------------------------------------------------------------
// Pass 3: local scan seeded with entry state; dt inline; fuses y = h.C + D*x
// and SiLU(z) gating; emits y bf16.
// ---------------------------------------------------------------------------
__global__ __launch_bounds__(256) void scan_pass3(
    const ushort_t* __restrict__ xsc, const ushort_t* __restrict__ xz,
    const float* __restrict__ xdbl, const float* __restrict__ dwt,
    const float* __restrict__ dtbias, const float* __restrict__ alt,
    const float* __restrict__ Dp, const float* __restrict__ hstate,
    ushort_t* __restrict__ y, int dir)
{
    int g = blockIdx.x % 3;
    int c = (blockIdx.x / 3) % NCHUNK;
    int b = blockIdx.x / (3 * NCHUNK);
    int d = g * 256 + threadIdx.x;
    size_t cidx = (size_t)(b * NCHUNK + c) * D_INNER + d;
    float A[D_STATE], h[D_STATE], w[DT_RANK];
    #pragma unroll
    for (int n = 0; n < D_STATE; n++) {
        A[n] = -__expf(alt[n * D_INNER + d]);
        h[n] = hstate[cidx * D_STATE + n];
    }
    #pragma unroll
    for (int r = 0; r < DT_RANK; r++) w[r] = dwt[r * D_INNER + d];
    float bias = dtbias[d];
    float Dd = Dp[d];
    size_t base = (size_t)b * SEQ;
    for (int i = 0; i < LCHUNK; i++) {
        int p = c * LCHUNK + i;
        int l = dir ? (SEQ - 1 - p) : p;
        size_t row = base + l;
        const float* xr = xdbl + row * XDBL_LD;
        float acc = bias;
        #pragma unroll
        for (int r = 0; r < DT_RANK; r++) acc = fmaf(xr[r], w[r], acc);
        float dtv = acc > 20.f ? acc : __logf(1.f + __expf(acc));
        float xv  = bf16_to_f32(xsc[row * D_INNER + d]);
        float zv  = bf16_to_f32(xz[row * 1536 + D_INNER + d]);
        float dtx = dtv * xv;
        const float* Br = xr + DT_RANK;
        const float* Cr = xr + DT_RANK + D_STATE;
        float yv = 0.f;
        #pragma unroll
        for (int n = 0; n < D_STATE; n++) {
            h[n] = fmaf(__expf(dtv * A[n]), h[n], dtx * Br[n]);
            yv = fmaf(h[n], Cr[n], yv);
        }
        yv = fmaf(xv, Dd, yv);
        float sg = 1.f / (1.f + __expf(-zv));
        yv *= zv * sg;
        y[row * D_INNER + d] = f32_to_bf16_rne(yv);
    }
}

// ---------------------------------------------------------------------------
extern "C" void kernel_launch(void* const* d_in, const int* in_sizes, int n_in,
                              void* d_out, int out_size, void* d_ws, size_t ws_size,
                              hipStream_t stream)
{
    const float* x       = (const float*)d_in[0];
    const float* norm_w  = (const float*)d_in[1];
    const float* norm_b  = (const float*)d_in[2];
    const float* in_proj = (const float*)d_in[3];
    const float* conv_w  = (const float*)d_in[4];
    const float* conv_b  = (const float*)d_in[5];
    const float* x_proj  = (const float*)d_in[6];
    const float* dt_w    = (const float*)d_in[7];
    const float* dt_b    = (const float*)d_in[8];
    const float* A_log   = (const float*)d_in[9];
    const float* Dp      = (const float*)d_in[10];
    const float* out_proj= (const float*)d_in[11];
    float* out = (float*)d_out;

    float* ws   = (float*)d_ws;
    // lnb (bf16 BL*384) and ybf (bf16 BL*768) share one region.
    float* reg0 = ws;                ws += (size_t)BL * D_INNER / 2;
    ushort_t* lnb = (ushort_t*)reg0;
    ushort_t* ybf = (ushort_t*)reg0;
    ushort_t* xzb  = (ushort_t*)ws;  ws += (size_t)BL * 1536 / 2;
    ushort_t* xscb = (ushort_t*)ws;  ws += (size_t)BL * D_INNER / 2;
    float* xdbl = ws;                ws += (size_t)BL * XDBL_LD;
    float* sumdt  = ws;              ws += (size_t)BATCH * NCHUNK * D_INNER;
    float* hstate = ws;              ws += (size_t)BATCH * NCHUNK * D_INNER * D_STATE;
    ushort_t* wbf_in  = (ushort_t*)ws;  ws += (size_t)2 * 1536 * D_MODEL / 2;
    ushort_t* wbf_out = (ushort_t*)ws;  ws += (size_t)2 * D_MODEL * D_INNER / 2;
    ushort_t* xp_bf   = (ushort_t*)ws;  ws += (size_t)2 * 64 * D_INNER / 2;
    float* cwt = ws;                 ws += (size_t)2 * K_CONV * D_INNER;
    float* alt = ws;                 ws += (size_t)2 * D_STATE * D_INNER;
    float* dwt = ws;                 ws += (size_t)2 * DT_RANK * D_INNER;

    // one-shot weight prep (casts + transposes), both directions
    cast_bf16_kernel<<<(2 * 1536 * D_MODEL + 255) / 256, 256, 0, stream>>>(
        in_proj, wbf_in, 2 * 1536 * D_MODEL);
    cast_bf16_kernel<<<(2 * D_MODEL * D_INNER + 255) / 256, 256, 0, stream>>>(
        out_proj, wbf_out, 2 * D_MODEL * D_INNER);
    cast_xproj_kernel<<<(2 * 64 * D_INNER + 255) / 256, 256, 0, stream>>>(
        x_proj, xp_bf);
    {
        int total = 2 * (K_CONV + D_STATE + DT_RANK) * D_INNER;
        prep_transpose_kernel<<<(total + 255) / 256, 256, 0, stream>>>(
            conv_w, A_log, dt_w, cwt, alt, dwt);
    }

    for (int i = 0; i < 2; i++) {
        const float* hinp = (i == 0) ? x : out;
        ln_kernel<<<BL, 384, 0, stream>>>(hinp, norm_w + i * D_MODEL,
                                          norm_b + i * D_MODEL, lnb);
        gemm_mfma_b16<<<dim3(BL / 128, 1536 / 128), 256, 0, stream>>>(
            lnb, wbf_in + (size_t)i * 1536 * D_MODEL, xzb, 1536, D_MODEL);
        conv_silu_kernel<<<(BL * 96) / 256, 256, 0, stream>>>(
            xzb, cwt + (size_t)i * K_CONV * D_INNER, conv_b + i * D_INNER,
            xscb, i);
        xdbl_mfma<<<BL / 128, 256, 0, stream>>>(
            xscb, xp_bf + (size_t)i * 64 * D_INNER, xdbl);
        scan_pass1<<<BATCH * NCHUNK * 3, 256, 0, stream>>>(
            xscb, xdbl, dwt + (size_t)i * DT_RANK * D_INNER,
            dt_b + i * D_INNER, alt + (size_t)i * D_STATE * D_INNER,
            hstate, sumdt, i);
        scan_pass2<<<(BATCH * D_INNER * D_STATE) / 256, 256, 0, stream>>>(
            hstate, sumdt, alt + (size_t)i * D_STATE * D_INNER);
        scan_pass3<<<BATCH * NCHUNK * 3, 256, 0, stream>>>(
            xscb, xzb, xdbl, dwt + (size_t)i * DT_RANK * D_INNER,
            dt_b + i * D_INNER, alt + (size_t)i * D_STATE * D_INNER,
            Dp + i * D_INNER, hstate, ybf, i);
        gemm_mfma_f32<<<dim3(BL / 128, D_MODEL / 128), 256, 0, stream>>>(
            ybf, wbf_out + (size_t)i * D_MODEL * D_INNER, hinp, out,
            D_MODEL, D_INNER);
    }
}

// Round 7
// 545.700 us; speedup vs baseline: 7.3887x; 1.0884x over previous
//
#include <hip/hip_runtime.h>
#include <hip/hip_bf16.h>
#include <cstddef>

#define D_MODEL 384
#define D_INNER 768
#define D_STATE 16
#define DT_RANK 24
#define K_CONV  4
#define BATCH   8
#define SEQ     2048
#define BL      (BATCH * SEQ)     // 16384 rows
#define NCHUNK  64
#define LCHUNK  (SEQ / NCHUNK)    // 32
#define XDBL_LD 64                // padded leading dim of x_dbl buffer
#define LOG2E   1.44269504088896f

typedef unsigned short ushort_t;
typedef __bf16 bf16x8 __attribute__((ext_vector_type(8)));
typedef float  f32x4  __attribute__((ext_vector_type(4)));
typedef unsigned short u16x8 __attribute__((ext_vector_type(8)));

#define GLOBAL_AS(p) ((const __attribute__((address_space(1))) void*)(p))
#define LDS_AS(p)    ((__attribute__((address_space(3))) void*)(p))

__device__ __forceinline__ ushort_t f32_to_bf16_rne(float v) {
    unsigned int u = __float_as_uint(v);
    return (ushort_t)((u + 0x7FFFu + ((u >> 16) & 1u)) >> 16);
}
__device__ __forceinline__ float bf16_to_f32(ushort_t u) {
    return __uint_as_float(((unsigned int)u) << 16);
}

// ---------------------------------------------------------------------------
// Elementwise f32 -> bf16 (RNE) for weights (both directions in one launch).
// ---------------------------------------------------------------------------
__global__ __launch_bounds__(256) void cast_bf16_kernel(
    const float* __restrict__ in, ushort_t* __restrict__ out, int n)
{
    int i = blockIdx.x * 256 + threadIdx.x;
    if (i < n) out[i] = f32_to_bf16_rne(in[i]);
}

// ---------------------------------------------------------------------------
// x_proj cast with zero-padding: (2,56,768) f32 -> (2,64,768) bf16.
// ---------------------------------------------------------------------------
__global__ __launch_bounds__(256) void cast_xproj_kernel(
    const float* __restrict__ in, ushort_t* __restrict__ out)
{
    int i = blockIdx.x * 256 + threadIdx.x;   // 2*64*768
    if (i >= 2 * 64 * D_INNER) return;
    int c   = i % D_INNER;
    int r   = (i / D_INNER) % 64;
    int dir = i / (64 * D_INNER);
    out[i] = (r < 56) ? f32_to_bf16_rne(in[((size_t)dir * 56 + r) * D_INNER + c])
                      : (ushort_t)0;
}

// ---------------------------------------------------------------------------
// Transpose small per-channel params to channel-contiguous layouts:
//   cwt[dir][k][768]  <- conv_w[dir][c][k]
//   alt[dir][n][768]  <- A_log[dir][d][n]
//   dwt[dir][r][768]  <- dt_w[dir][d][r]
// ---------------------------------------------------------------------------
__global__ __launch_bounds__(256) void prep_transpose_kernel(
    const float* __restrict__ conv_w, const float* __restrict__ A_log,
    const float* __restrict__ dt_w, float* __restrict__ cwt,
    float* __restrict__ alt, float* __restrict__ dwt)
{
    int i = blockIdx.x * 256 + threadIdx.x;
    const int NCW = 2 * K_CONV * D_INNER;          // 6144
    const int NAL = 2 * D_STATE * D_INNER;         // 24576
    const int NDW = 2 * DT_RANK * D_INNER;         // 36864
    if (i < NCW) {
        int c = i % D_INNER, k = (i / D_INNER) % K_CONV, dir = i / (K_CONV * D_INNER);
        cwt[i] = conv_w[((size_t)dir * D_INNER + c) * K_CONV + k];
    } else if (i < NCW + NAL) {
        int j = i - NCW;
        int d = j % D_INNER, n = (j / D_INNER) % D_STATE, dir = j / (D_STATE * D_INNER);
        alt[j] = A_log[((size_t)dir * D_INNER + d) * D_STATE + n];
    } else if (i < NCW + NAL + NDW) {
        int j = i - NCW - NAL;
        int d = j % D_INNER, r = (j / D_INNER) % DT_RANK, dir = j / (DT_RANK * D_INNER);
        dwt[j] = dt_w[((size_t)dir * D_INNER + d) * DT_RANK + r];
    }
}

// ---------------------------------------------------------------------------
// LayerNorm over last dim (384), output bf16. One block per row, 384 thr.
// ---------------------------------------------------------------------------
__global__ __launch_bounds__(384) void ln_kernel(
    const float* __restrict__ in, const float* __restrict__ w,
    const float* __restrict__ b, ushort_t* __restrict__ out)
{
    int row = blockIdx.x;
    int tid = threadIdx.x;
    float v = in[(size_t)row * D_MODEL + tid];
    float s = v, sq = v * v;
    #pragma unroll
    for (int o = 32; o; o >>= 1) {
        s  += __shfl_down(s, o);
        sq += __shfl_down(sq, o);
    }
    __shared__ float ss[6], ssq[6];
    __shared__ float mb[2];
    int wid = tid >> 6;
    if ((tid & 63) == 0) { ss[wid] = s; ssq[wid] = sq; }
    __syncthreads();
    if (tid == 0) {
        float S = 0.f, Q = 0.f;
        #pragma unroll
        for (int k = 0; k < 6; k++) { S += ss[k]; Q += ssq[k]; }
        float mu  = S * (1.0f / D_MODEL);
        float var = Q * (1.0f / D_MODEL) - mu * mu;
        mb[0] = mu;
        mb[1] = rsqrtf(var + 1e-5f);
    }
    __syncthreads();
    float r = (v - mb[0]) * mb[1] * w[tid] + b[tid];
    out[(size_t)row * D_MODEL + tid] = f32_to_bf16_rne(r);
}

// ---------------------------------------------------------------------------
// bf16 MFMA GEMM, bf16 output: C = A (MxK) * W^T (W NxK). 128x128 tile,
// BK=32, 4 waves each owning a 64x64 quadrant.
// ---------------------------------------------------------------------------
__global__ __launch_bounds__(256) void gemm_mfma_b16(
    const ushort_t* __restrict__ A, const ushort_t* __restrict__ W,
    ushort_t* __restrict__ C, int N, int K)
{
    __shared__ __bf16 As[128 * 32];
    __shared__ __bf16 Ws[128 * 32];
    int tid  = threadIdx.x;
    int bm = blockIdx.x, bn = blockIdx.y;
    int lane = tid & 63, wave = tid >> 6;
    int wr = wave >> 1, wc = wave & 1;
    int quad = lane >> 4, l16 = lane & 15;

    const ushort_t* Ag = A + (size_t)(bm * 128 + (tid >> 2)) * K + (tid & 3) * 8;
    const ushort_t* Wg = W + (size_t)(bn * 128 + (tid >> 2)) * K + (tid & 3) * 8;

    f32x4 acc[4][4] = {};

    for (int k0 = 0; k0 < K; k0 += 32) {
        __syncthreads();
        __builtin_amdgcn_global_load_lds(GLOBAL_AS(Ag + k0),
                                         LDS_AS(As + tid * 8), 16, 0, 0);
        __builtin_amdgcn_global_load_lds(GLOBAL_AS(Ag + (size_t)64 * K + k0),
                                         LDS_AS(As + 2048 + tid * 8), 16, 0, 0);
        __builtin_amdgcn_global_load_lds(GLOBAL_AS(Wg + k0),
                                         LDS_AS(Ws + tid * 8), 16, 0, 0);
        __builtin_amdgcn_global_load_lds(GLOBAL_AS(Wg + (size_t)64 * K + k0),
                                         LDS_AS(Ws + 2048 + tid * 8), 16, 0, 0);
        __syncthreads();

        bf16x8 af[4], wf[4];
        #pragma unroll
        for (int i = 0; i < 4; i++)
            af[i] = *(const bf16x8*)(As + (wr * 64 + i * 16 + l16) * 32 + quad * 8);
        #pragma unroll
        for (int j = 0; j < 4; j++)
            wf[j] = *(const bf16x8*)(Ws + (wc * 64 + j * 16 + l16) * 32 + quad * 8);
        #pragma unroll
        for (int i = 0; i < 4; i++)
            #pragma unroll
            for (int j = 0; j < 4; j++)
                acc[i][j] = __builtin_amdgcn_mfma_f32_16x16x32_bf16(
                    af[i], wf[j], acc[i][j], 0, 0, 0);
    }

    #pragma unroll
    for (int i = 0; i < 4; i++) {
        #pragma unroll
        for (int r = 0; r < 4; r++) {
            int row = bm * 128 + wr * 64 + i * 16 + quad * 4 + r;
            #pragma unroll
            for (int j = 0; j < 4; j++) {
                int col = bn * 128 + wc * 64 + j * 16 + l16;
                C[(size_t)row * N + col] = f32_to_bf16_rne(acc[i][j][r]);
            }
        }
    }
}

// ---------------------------------------------------------------------------
// bf16 MFMA GEMM, f32 output + f32 residual add (for out_proj).
// ---------------------------------------------------------------------------
__global__ __launch_bounds__(256) void gemm_mfma_f32(
    const ushort_t* __restrict__ A, const ushort_t* __restrict__ W,
    const float* __restrict__ resid, float* __restrict__ C, int N, int K)
{
    __shared__ __bf16 As[128 * 32];
    __shared__ __bf16 Ws[128 * 32];
    int tid  = threadIdx.x;
    int bm = blockIdx.x, bn = blockIdx.y;
    int lane = tid & 63, wave = tid >> 6;
    int wr = wave >> 1, wc = wave & 1;
    int quad = lane >> 4, l16 = lane & 15;

    const ushort_t* Ag = A + (size_t)(bm * 128 + (tid >> 2)) * K + (tid & 3) * 8;
    const ushort_t* Wg = W + (size_t)(bn * 128 + (tid >> 2)) * K + (tid & 3) * 8;

    f32x4 acc[4][4] = {};

    for (int k0 = 0; k0 < K; k0 += 32) {
        __syncthreads();
        __builtin_amdgcn_global_load_lds(GLOBAL_AS(Ag + k0),
                                         LDS_AS(As + tid * 8), 16, 0, 0);
        __builtin_amdgcn_global_load_lds(GLOBAL_AS(Ag + (size_t)64 * K + k0),
                                         LDS_AS(As + 2048 + tid * 8), 16, 0, 0);
        __builtin_amdgcn_global_load_lds(GLOBAL_AS(Wg + k0),
                                         LDS_AS(Ws + tid * 8), 16, 0, 0);
        __builtin_amdgcn_global_load_lds(GLOBAL_AS(Wg + (size_t)64 * K + k0),
                                         LDS_AS(Ws + 2048 + tid * 8), 16, 0, 0);
        __syncthreads();

        bf16x8 af[4], wf[4];
        #pragma unroll
        for (int i = 0; i < 4; i++)
            af[i] = *(const bf16x8*)(As + (wr * 64 + i * 16 + l16) * 32 + quad * 8);
        #pragma unroll
        for (int j = 0; j < 4; j++)
            wf[j] = *(const bf16x8*)(Ws + (wc * 64 + j * 16 + l16) * 32 + quad * 8);
        #pragma unroll
        for (int i = 0; i < 4; i++)
            #pragma unroll
            for (int j = 0; j < 4; j++)
                acc[i][j] = __builtin_amdgcn_mfma_f32_16x16x32_bf16(
                    af[i], wf[j], acc[i][j], 0, 0, 0);
    }

    #pragma unroll
    for (int i = 0; i < 4; i++) {
        #pragma unroll
        for (int r = 0; r < 4; r++) {
            int row = bm * 128 + wr * 64 + i * 16 + quad * 4 + r;
            #pragma unroll
            for (int j = 0; j < 4; j++) {
                int col = bn * 128 + wc * 64 + j * 16 + l16;
                size_t idx = (size_t)row * N + col;
                C[idx] = acc[i][j][r] + resid[idx];
            }
        }
    }
}

// ---------------------------------------------------------------------------
// x_dbl = xs(bf16) @ x_proj^T(bf16, 64x768 zero-padded), f32 out (BLx64).
// ---------------------------------------------------------------------------
__global__ __launch_bounds__(256) void xdbl_mfma(
    const ushort_t* __restrict__ A, const ushort_t* __restrict__ W,
    float* __restrict__ C)
{
    __shared__ __bf16 As[128 * 32];
    __shared__ __bf16 Ws[64 * 32];
    int tid  = threadIdx.x;
    int bm = blockIdx.x;
    int lane = tid & 63, wave = tid >> 6;
    int quad = lane >> 4, l16 = lane & 15;

    const ushort_t* Ag = A + (size_t)(bm * 128 + (tid >> 2)) * D_INNER + (tid & 3) * 8;
    const ushort_t* Wg = W + (size_t)(tid >> 2) * D_INNER + (tid & 3) * 8;

    f32x4 acc[2][4] = {};

    for (int k0 = 0; k0 < D_INNER; k0 += 32) {
        __syncthreads();
        __builtin_amdgcn_global_load_lds(GLOBAL_AS(Ag + k0),
                                         LDS_AS(As + tid * 8), 16, 0, 0);
        __builtin_amdgcn_global_load_lds(GLOBAL_AS(Ag + (size_t)64 * D_INNER + k0),
                                         LDS_AS(As + 2048 + tid * 8), 16, 0, 0);
        __builtin_amdgcn_global_load_lds(GLOBAL_AS(Wg + k0),
                                         LDS_AS(Ws + tid * 8), 16, 0, 0);
        __syncthreads();

        bf16x8 af[2], wf[4];
        #pragma unroll
        for (int i = 0; i < 2; i++)
            af[i] = *(const bf16x8*)(As + (wave * 32 + i * 16 + l16) * 32 + quad * 8);
        #pragma unroll
        for (int j = 0; j < 4; j++)
            wf[j] = *(const bf16x8*)(Ws + (j * 16 + l16) * 32 + quad * 8);
        #pragma unroll
        for (int i = 0; i < 2; i++)
            #pragma unroll
            for (int j = 0; j < 4; j++)
                acc[i][j] = __builtin_amdgcn_mfma_f32_16x16x32_bf16(
                    af[i], wf[j], acc[i][j], 0, 0, 0);
    }

    #pragma unroll
    for (int i = 0; i < 2; i++) {
        #pragma unroll
        for (int r = 0; r < 4; r++) {
            int row = bm * 128 + wave * 32 + i * 16 + quad * 4 + r;
            #pragma unroll
            for (int j = 0; j < 4; j++) {
                int col = j * 16 + l16;
                C[(size_t)row * XDBL_LD + col] = acc[i][j][r];
            }
        }
    }
}

// ---------------------------------------------------------------------------
// dt = softplus(xdbl[:,0:24] @ dwt + bias), bf16 out. One block = 16 rows x
// one 256-wide d-slice. Weights from transposed dwt[r][768] (coalesced).
// ---------------------------------------------------------------------------
__global__ __launch_bounds__(256) void dt_kernel(
    const float* __restrict__ xdbl, const float* __restrict__ dwt,
    const float* __restrict__ dtbias, ushort_t* __restrict__ dtb)
{
    int g    = blockIdx.x % 3;
    int row0 = (blockIdx.x / 3) * 16;
    int tid  = threadIdx.x;
    int d    = g * 256 + tid;
    float w[DT_RANK];
    #pragma unroll
    for (int r = 0; r < DT_RANK; r++) w[r] = dwt[r * D_INNER + d];
    float bias = dtbias[d];
    __shared__ float xd[16][DT_RANK];
    if (tid < 16 * DT_RANK) {
        int rr = tid / DT_RANK, cc = tid % DT_RANK;
        xd[rr][cc] = xdbl[(size_t)(row0 + rr) * XDBL_LD + cc];
    }
    __syncthreads();
    #pragma unroll 4
    for (int i = 0; i < 16; i++) {
        float acc = bias;
        #pragma unroll
        for (int r = 0; r < DT_RANK; r++) acc = fmaf(xd[i][r], w[r], acc);
        float sp = acc > 20.f ? acc : __logf(1.f + __expf(acc));
        dtb[(size_t)(row0 + i) * D_INNER + d] = f32_to_bf16_rne(sp);
    }
}

// ---------------------------------------------------------------------------
// Causal depthwise conv (k=4) + bias + SiLU, bf16 in/out, 8 ch per thread.
// ---------------------------------------------------------------------------
__global__ __launch_bounds__(256) void conv_silu_kernel(
    const ushort_t* __restrict__ xz, const float* __restrict__ cwt,
    const float* __restrict__ cb, ushort_t* __restrict__ xsc, int dir)
{
    int idx8 = blockIdx.x * 256 + threadIdx.x;   // BL * 96
    int c8   = (idx8 % 96) * 8;
    int row  = idx8 / 96;
    int l    = row % SEQ;
    int b0   = row - l;

    float acc[8];
    float4 bv0 = *(const float4*)(cb + c8);
    float4 bv1 = *(const float4*)(cb + c8 + 4);
    acc[0] = bv0.x; acc[1] = bv0.y; acc[2] = bv0.z; acc[3] = bv0.w;
    acc[4] = bv1.x; acc[5] = bv1.y; acc[6] = bv1.z; acc[7] = bv1.w;

    #pragma unroll
    for (int k = 0; k < 4; k++) {
        int ls = dir ? (l + k) : (l - 3 + k);
        int wk = dir ? (3 - k) : k;
        bool ok = dir ? (ls < SEQ) : (ls >= 0);
        if (ok) {
            u16x8 v = *(const u16x8*)(xz + (size_t)(b0 + ls) * 1536 + c8);
            float4 w0 = *(const float4*)(cwt + wk * D_INNER + c8);
            float4 w1 = *(const float4*)(cwt + wk * D_INNER + c8 + 4);
            float wv[8] = {w0.x, w0.y, w0.z, w0.w, w1.x, w1.y, w1.z, w1.w};
            #pragma unroll
            for (int j = 0; j < 8; j++)
                acc[j] = fmaf(bf16_to_f32(v[j]), wv[j], acc[j]);
        }
    }
    u16x8 o;
    #pragma unroll
    for (int j = 0; j < 8; j++) {
        float sg = 1.0f / (1.0f + __expf(-acc[j]));
        o[j] = f32_to_bf16_rne(acc[j] * sg);
    }
    *(u16x8*)(xsc + (size_t)row * D_INNER + c8) = o;
}

// ---------------------------------------------------------------------------
// Chunked selective scan, pass 1: per-chunk local scan from h=0.
// dt from precomputed bf16 buffer; A2 = -exp(A_log)*log2(e) -> exp2.
// ---------------------------------------------------------------------------
__global__ __launch_bounds__(256) void scan_pass1(
    const ushort_t* __restrict__ xsc, const ushort_t* __restrict__ dtb,
    const float* __restrict__ xdbl, const float* __restrict__ alt,
    float* __restrict__ hstate, float* __restrict__ sumdt_buf, int dir)
{
    int g = blockIdx.x % 3;
    int c = (blockIdx.x / 3) % NCHUNK;
    int b = blockIdx.x / (3 * NCHUNK);
    int d = g * 256 + threadIdx.x;
    float A2[D_STATE];
    #pragma unroll
    for (int n = 0; n < D_STATE; n++)
        A2[n] = -__expf(alt[n * D_INNER + d]) * LOG2E;
    float h[D_STATE] = {};
    float sdt = 0.f;
    size_t base = (size_t)b * SEQ;
    for (int i = 0; i < LCHUNK; i++) {
        int p = c * LCHUNK + i;
        int l = dir ? (SEQ - 1 - p) : p;
        size_t row = base + l;
        float dtv = bf16_to_f32(dtb[row * D_INNER + d]);
        float xv  = bf16_to_f32(xsc[row * D_INNER + d]);
        float dtx = dtv * xv;
        sdt += dtv;
        const float* Br = xdbl + row * XDBL_LD + DT_RANK;
        #pragma unroll
        for (int n = 0; n < D_STATE; n++)
            h[n] = fmaf(__builtin_amdgcn_exp2f(dtv * A2[n]), h[n], dtx * Br[n]);
    }
    size_t cidx = (size_t)(b * NCHUNK + c) * D_INNER + d;
    sumdt_buf[cidx] = sdt;
    #pragma unroll
    for (int n = 0; n < D_STATE; n++) hstate[cidx * D_STATE + n] = h[n];
}

// ---------------------------------------------------------------------------
// Pass 2: in-place combine; hstate[c] becomes the ENTRY state of chunk c.
// ---------------------------------------------------------------------------
__global__ __launch_bounds__(256) void scan_pass2(
    float* __restrict__ hstate, const float* __restrict__ sumdt_buf,
    const float* __restrict__ alt)
{
    int gid = blockIdx.x * 256 + threadIdx.x;   // BATCH * D_INNER * 16
    int n = gid & 15;
    int d = (gid >> 4) % D_INNER;
    int b = gid / (16 * D_INNER);
    float A2 = -__expf(alt[n * D_INNER + d]) * LOG2E;
    float h = 0.f;
    for (int c = 0; c < NCHUNK; c++) {
        size_t cidx = (size_t)(b * NCHUNK + c) * D_INNER + d;
        float ho = hstate[cidx * D_STATE + n];
        hstate[cidx * D_STATE + n] = h;
        h = fmaf(__builtin_amdgcn_exp2f(A2 * sumdt_buf[cidx]), h, ho);
    }
}

// ---------------------------------------------------------------------------
// Pass 3: local scan seeded with entry state; fuses y = h.C + D*x and
// SiLU(z) gating; emits y bf16.
// ---------------------------------------------------------------------------
__global__ __launch_bounds__(256) void scan_pass3(
    const ushort_t* __restrict__ xsc, const ushort_t* __restrict__ dtb,
    const ushort_t* __restrict__ xz, const float* __restrict__ xdbl,
    const float* __restrict__ alt, const float* __restrict__ Dp,
    const float* __restrict__ hstate, ushort_t* __restrict__ y, int dir)
{
    int g = blockIdx.x % 3;
    int c = (blockIdx.x / 3) % NCHUNK;
    int b = blockIdx.x / (3 * NCHUNK);
    int d = g * 256 + threadIdx.x;
    size_t cidx = (size_t)(b * NCHUNK + c) * D_INNER + d;
    float A2[D_STATE], h[D_STATE];
    #pragma unroll
    for (int n = 0; n < D_STATE; n++) {
        A2[n] = -__expf(alt[n * D_INNER + d]) * LOG2E;
        h[n] = hstate[cidx * D_STATE + n];
    }
    float Dd = Dp[d];
    size_t base = (size_t)b * SEQ;
    for (int i = 0; i < LCHUNK; i++) {
        int p = c * LCHUNK + i;
        int l = dir ? (SEQ - 1 - p) : p;
        size_t row = base + l;
        float dtv = bf16_to_f32(dtb[row * D_INNER + d]);
        float xv  = bf16_to_f32(xsc[row * D_INNER + d]);
        float zv  = bf16_to_f32(xz[row * 1536 + D_INNER + d]);
        float dtx = dtv * xv;
        const float* Br = xdbl + row * XDBL_LD + DT_RANK;
        const float* Cr = xdbl + row * XDBL_LD + DT_RANK + D_STATE;
        float yv = 0.f;
        #pragma unroll
        for (int n = 0; n < D_STATE; n++) {
            h[n] = fmaf(__builtin_amdgcn_exp2f(dtv * A2[n]), h[n], dtx * Br[n]);
            yv = fmaf(h[n], Cr[n], yv);
        }
        yv = fmaf(xv, Dd, yv);
        float sg = 1.f / (1.f + __expf(-zv));
        yv *= zv * sg;
        y[row * D_INNER + d] = f32_to_bf16_rne(yv);
    }
}

// ---------------------------------------------------------------------------
extern "C" void kernel_launch(void* const* d_in, const int* in_sizes, int n_in,
                              void* d_out, int out_size, void* d_ws, size_t ws_size,
                              hipStream_t stream)
{
    const float* x       = (const float*)d_in[0];
    const float* norm_w  = (const float*)d_in[1];
    const float* norm_b  = (const float*)d_in[2];
    const float* in_proj = (const float*)d_in[3];
    const float* conv_w  = (const float*)d_in[4];
    const float* conv_b  = (const float*)d_in[5];
    const float* x_proj  = (const float*)d_in[6];
    const float* dt_w    = (const float*)d_in[7];
    const float* dt_b    = (const float*)d_in[8];
    const float* A_log   = (const float*)d_in[9];
    const float* Dp      = (const float*)d_in[10];
    const float* out_proj= (const float*)d_in[11];
    float* out = (float*)d_out;

    float* ws   = (float*)d_ws;
    // lnb (bf16 BL*384) and ybf (bf16 BL*768) share one region.
    float* reg0 = ws;                ws += (size_t)BL * D_INNER / 2;
    ushort_t* lnb = (ushort_t*)reg0;
    ushort_t* ybf = (ushort_t*)reg0;
    ushort_t* xzb  = (ushort_t*)ws;  ws += (size_t)BL * 1536 / 2;
    ushort_t* xscb = (ushort_t*)ws;  ws += (size_t)BL * D_INNER / 2;
    ushort_t* dtb  = (ushort_t*)ws;  ws += (size_t)BL * D_INNER / 2;
    float* xdbl = ws;                ws += (size_t)BL * XDBL_LD;
    float* sumdt  = ws;              ws += (size_t)BATCH * NCHUNK * D_INNER;
    float* hstate = ws;              ws += (size_t)BATCH * NCHUNK * D_INNER * D_STATE;
    ushort_t* wbf_in  = (ushort_t*)ws;  ws += (size_t)2 * 1536 * D_MODEL / 2;
    ushort_t* wbf_out = (ushort_t*)ws;  ws += (size_t)2 * D_MODEL * D_INNER / 2;
    ushort_t* xp_bf   = (ushort_t*)ws;  ws += (size_t)2 * 64 * D_INNER / 2;
    float* cwt = ws;                 ws += (size_t)2 * K_CONV * D_INNER;
    float* alt = ws;                 ws += (size_t)2 * D_STATE * D_INNER;
    float* dwt = ws;                 ws += (size_t)2 * DT_RANK * D_INNER;

    // one-shot weight prep (casts + transposes), both directions
    cast_bf16_kernel<<<(2 * 1536 * D_MODEL + 255) / 256, 256, 0, stream>>>(
        in_proj, wbf_in, 2 * 1536 * D_MODEL);
    cast_bf16_kernel<<<(2 * D_MODEL * D_INNER + 255) / 256, 256, 0, stream>>>(
        out_proj, wbf_out, 2 * D_MODEL * D_INNER);
    cast_xproj_kernel<<<(2 * 64 * D_INNER + 255) / 256, 256, 0, stream>>>(
        x_proj, xp_bf);
    {
        int total = 2 * (K_CONV + D_STATE + DT_RANK) * D_INNER;
        prep_transpose_kernel<<<(total + 255) / 256, 256, 0, stream>>>(
            conv_w, A_log, dt_w, cwt, alt, dwt);
    }

    for (int i = 0; i < 2; i++) {
        const float* hinp = (i == 0) ? x : out;
        ln_kernel<<<BL, 384, 0, stream>>>(hinp, norm_w + i * D_MODEL,
                                          norm_b + i * D_MODEL, lnb);
        gemm_mfma_b16<<<dim3(BL / 128, 1536 / 128), 256, 0, stream>>>(
            lnb, wbf_in + (size_t)i * 1536 * D_MODEL, xzb, 1536, D_MODEL);
        conv_silu_kernel<<<(BL * 96) / 256, 256, 0, stream>>>(
            xzb, cwt + (size_t)i * K_CONV * D_INNER, conv_b + i * D_INNER,
            xscb, i);
        xdbl_mfma<<<BL / 128, 256, 0, stream>>>(
            xscb, xp_bf + (size_t)i * 64 * D_INNER, xdbl);
        dt_kernel<<<(BL / 16) * 3, 256, 0, stream>>>(
            xdbl, dwt + (size_t)i * DT_RANK * D_INNER, dt_b + i * D_INNER, dtb);
        scan_pass1<<<BATCH * NCHUNK * 3, 256, 0, stream>>>(
            xscb, dtb, xdbl, alt + (size_t)i * D_STATE * D_INNER,
            hstate, sumdt, i);
        scan_pass2<<<(BATCH * D_INNER * D_STATE) / 256, 256, 0, stream>>>(
            hstate, sumdt, alt + (size_t)i * D_STATE * D_INNER);
        scan_pass3<<<BATCH * NCHUNK * 3, 256, 0, stream>>>(
            xscb, dtb, xzb, xdbl, alt + (size_t)i * D_STATE * D_INNER,
            Dp + i * D_INNER, hstate, ybf, i);
        gemm_mfma_f32<<<dim3(BL / 128, D_MODEL / 128), 256, 0, stream>>>(
            ybf, wbf_out + (size_t)i * D_MODEL * D_INNER, hinp, out,
            D_MODEL, D_INNER);
    }
}

// Round 8
// 498.374 us; speedup vs baseline: 8.0903x; 1.0950x over previous
//
#include <hip/hip_runtime.h>
#include <hip/hip_bf16.h>
#include <cstddef>

#define D_MODEL 384
#define D_INNER 768
#define D_STATE 16
#define DT_RANK 24
#define K_CONV  4
#define BATCH   8
#define SEQ     2048
#define BL      (BATCH * SEQ)     // 16384 rows
#define NCHUNK  64
#define LCHUNK  (SEQ / NCHUNK)    // 32
#define XDBL_LD 64                // padded leading dim of x_dbl buffer
#define LOG2E   1.44269504088896f

typedef unsigned short ushort_t;
typedef __bf16 bf16x8 __attribute__((ext_vector_type(8)));
typedef float  f32x4  __attribute__((ext_vector_type(4)));
typedef unsigned short u16x8 __attribute__((ext_vector_type(8)));

#define GLOBAL_AS(p) ((const __attribute__((address_space(1))) void*)(p))
#define LDS_AS(p)    ((__attribute__((address_space(3))) void*)(p))

__device__ __forceinline__ ushort_t f32_to_bf16_rne(float v) {
    unsigned int u = __float_as_uint(v);
    return (ushort_t)((u + 0x7FFFu + ((u >> 16) & 1u)) >> 16);
}
__device__ __forceinline__ float bf16_to_f32(ushort_t u) {
    return __uint_as_float(((unsigned int)u) << 16);
}

// ---------------------------------------------------------------------------
// Elementwise f32 -> bf16 (RNE) for weights (both directions in one launch).
// ---------------------------------------------------------------------------
__global__ __launch_bounds__(256) void cast_bf16_kernel(
    const float* __restrict__ in, ushort_t* __restrict__ out, int n)
{
    int i = blockIdx.x * 256 + threadIdx.x;
    if (i < n) out[i] = f32_to_bf16_rne(in[i]);
}

// ---------------------------------------------------------------------------
// x_proj cast with zero-padding: (2,56,768) f32 -> (2,64,768) bf16.
// ---------------------------------------------------------------------------
__global__ __launch_bounds__(256) void cast_xproj_kernel(
    const float* __restrict__ in, ushort_t* __restrict__ out)
{
    int i = blockIdx.x * 256 + threadIdx.x;   // 2*64*768
    if (i >= 2 * 64 * D_INNER) return;
    int c   = i % D_INNER;
    int r   = (i / D_INNER) % 64;
    int dir = i / (64 * D_INNER);
    out[i] = (r < 56) ? f32_to_bf16_rne(in[((size_t)dir * 56 + r) * D_INNER + c])
                      : (ushort_t)0;
}

// ---------------------------------------------------------------------------
// Transpose small per-channel params to channel-contiguous layouts:
//   cwt[dir][k][768]  <- conv_w[dir][c][k]
//   alt[dir][n][768]  <- A_log[dir][d][n]
//   dwt[dir][r][768]  <- dt_w[dir][d][r]
// ---------------------------------------------------------------------------
__global__ __launch_bounds__(256) void prep_transpose_kernel(
    const float* __restrict__ conv_w, const float* __restrict__ A_log,
    const float* __restrict__ dt_w, float* __restrict__ cwt,
    float* __restrict__ alt, float* __restrict__ dwt)
{
    int i = blockIdx.x * 256 + threadIdx.x;
    const int NCW = 2 * K_CONV * D_INNER;          // 6144
    const int NAL = 2 * D_STATE * D_INNER;         // 24576
    const int NDW = 2 * DT_RANK * D_INNER;         // 36864
    if (i < NCW) {
        int c = i % D_INNER, k = (i / D_INNER) % K_CONV, dir = i / (K_CONV * D_INNER);
        cwt[i] = conv_w[((size_t)dir * D_INNER + c) * K_CONV + k];
    } else if (i < NCW + NAL) {
        int j = i - NCW;
        int d = j % D_INNER, n = (j / D_INNER) % D_STATE, dir = j / (D_STATE * D_INNER);
        alt[j] = A_log[((size_t)dir * D_INNER + d) * D_STATE + n];
    } else if (i < NCW + NAL + NDW) {
        int j = i - NCW - NAL;
        int d = j % D_INNER, r = (j / D_INNER) % DT_RANK, dir = j / (DT_RANK * D_INNER);
        dwt[j] = dt_w[((size_t)dir * D_INNER + d) * DT_RANK + r];
    }
}

// ---------------------------------------------------------------------------
// Detect the structured-A fast path: exp(A_log[d][n]) == n+1 (per direction).
// flags[dir] = 1 if the whole direction matches within 1e-4 relative.
// ---------------------------------------------------------------------------
__global__ __launch_bounds__(256) void check_A_kernel(
    const float* __restrict__ A_log, int* __restrict__ flags)
{
    __shared__ int ok[2];
    int tid = threadIdx.x;
    if (tid < 2) ok[tid] = 1;
    __syncthreads();
    for (int dir = 0; dir < 2; dir++) {
        bool good = true;
        for (int j = tid; j < D_INNER * D_STATE; j += 256) {
            int n = j % D_STATE;
            float v = __expf(A_log[(size_t)dir * D_INNER * D_STATE + j]);
            good = good && (fabsf(v - (float)(n + 1)) <= 1e-4f * (float)(n + 1));
        }
        if (!good) atomicAnd(&ok[dir], 0);
    }
    __syncthreads();
    if (tid < 2) flags[tid] = ok[tid];
}

// ---------------------------------------------------------------------------
// LayerNorm over last dim (384), output bf16. One block per row, 384 thr.
// ---------------------------------------------------------------------------
__global__ __launch_bounds__(384) void ln_kernel(
    const float* __restrict__ in, const float* __restrict__ w,
    const float* __restrict__ b, ushort_t* __restrict__ out)
{
    int row = blockIdx.x;
    int tid = threadIdx.x;
    float v = in[(size_t)row * D_MODEL + tid];
    float s = v, sq = v * v;
    #pragma unroll
    for (int o = 32; o; o >>= 1) {
        s  += __shfl_down(s, o);
        sq += __shfl_down(sq, o);
    }
    __shared__ float ss[6], ssq[6];
    __shared__ float mb[2];
    int wid = tid >> 6;
    if ((tid & 63) == 0) { ss[wid] = s; ssq[wid] = sq; }
    __syncthreads();
    if (tid == 0) {
        float S = 0.f, Q = 0.f;
        #pragma unroll
        for (int k = 0; k < 6; k++) { S += ss[k]; Q += ssq[k]; }
        float mu  = S * (1.0f / D_MODEL);
        float var = Q * (1.0f / D_MODEL) - mu * mu;
        mb[0] = mu;
        mb[1] = rsqrtf(var + 1e-5f);
    }
    __syncthreads();
    float r = (v - mb[0]) * mb[1] * w[tid] + b[tid];
    out[(size_t)row * D_MODEL + tid] = f32_to_bf16_rne(r);
}

// ---------------------------------------------------------------------------
// bf16 MFMA GEMM, bf16 output: C = A (MxK) * W^T (W NxK). 128x128 tile,
// BK=32, 4 waves each owning a 64x64 quadrant.
// ---------------------------------------------------------------------------
__global__ __launch_bounds__(256) void gemm_mfma_b16(
    const ushort_t* __restrict__ A, const ushort_t* __restrict__ W,
    ushort_t* __restrict__ C, int N, int K)
{
    __shared__ __bf16 As[128 * 32];
    __shared__ __bf16 Ws[128 * 32];
    int tid  = threadIdx.x;
    int bm = blockIdx.x, bn = blockIdx.y;
    int lane = tid & 63, wave = tid >> 6;
    int wr = wave >> 1, wc = wave & 1;
    int quad = lane >> 4, l16 = lane & 15;

    const ushort_t* Ag = A + (size_t)(bm * 128 + (tid >> 2)) * K + (tid & 3) * 8;
    const ushort_t* Wg = W + (size_t)(bn * 128 + (tid >> 2)) * K + (tid & 3) * 8;

    f32x4 acc[4][4] = {};

    for (int k0 = 0; k0 < K; k0 += 32) {
        __syncthreads();
        __builtin_amdgcn_global_load_lds(GLOBAL_AS(Ag + k0),
                                         LDS_AS(As + tid * 8), 16, 0, 0);
        __builtin_amdgcn_global_load_lds(GLOBAL_AS(Ag + (size_t)64 * K + k0),
                                         LDS_AS(As + 2048 + tid * 8), 16, 0, 0);
        __builtin_amdgcn_global_load_lds(GLOBAL_AS(Wg + k0),
                                         LDS_AS(Ws + tid * 8), 16, 0, 0);
        __builtin_amdgcn_global_load_lds(GLOBAL_AS(Wg + (size_t)64 * K + k0),
                                         LDS_AS(Ws + 2048 + tid * 8), 16, 0, 0);
        __syncthreads();

        bf16x8 af[4], wf[4];
        #pragma unroll
        for (int i = 0; i < 4; i++)
            af[i] = *(const bf16x8*)(As + (wr * 64 + i * 16 + l16) * 32 + quad * 8);
        #pragma unroll
        for (int j = 0; j < 4; j++)
            wf[j] = *(const bf16x8*)(Ws + (wc * 64 + j * 16 + l16) * 32 + quad * 8);
        #pragma unroll
        for (int i = 0; i < 4; i++)
            #pragma unroll
            for (int j = 0; j < 4; j++)
                acc[i][j] = __builtin_amdgcn_mfma_f32_16x16x32_bf16(
                    af[i], wf[j], acc[i][j], 0, 0, 0);
    }

    #pragma unroll
    for (int i = 0; i < 4; i++) {
        #pragma unroll
        for (int r = 0; r < 4; r++) {
            int row = bm * 128 + wr * 64 + i * 16 + quad * 4 + r;
            #pragma unroll
            for (int j = 0; j < 4; j++) {
                int col = bn * 128 + wc * 64 + j * 16 + l16;
                C[(size_t)row * N + col] = f32_to_bf16_rne(acc[i][j][r]);
            }
        }
    }
}

// ---------------------------------------------------------------------------
// bf16 MFMA GEMM, f32 output + f32 residual add (for out_proj).
// ---------------------------------------------------------------------------
__global__ __launch_bounds__(256) void gemm_mfma_f32(
    const ushort_t* __restrict__ A, const ushort_t* __restrict__ W,
    const float* __restrict__ resid, float* __restrict__ C, int N, int K)
{
    __shared__ __bf16 As[128 * 32];
    __shared__ __bf16 Ws[128 * 32];
    int tid  = threadIdx.x;
    int bm = blockIdx.x, bn = blockIdx.y;
    int lane = tid & 63, wave = tid >> 6;
    int wr = wave >> 1, wc = wave & 1;
    int quad = lane >> 4, l16 = lane & 15;

    const ushort_t* Ag = A + (size_t)(bm * 128 + (tid >> 2)) * K + (tid & 3) * 8;
    const ushort_t* Wg = W + (size_t)(bn * 128 + (tid >> 2)) * K + (tid & 3) * 8;

    f32x4 acc[4][4] = {};

    for (int k0 = 0; k0 < K; k0 += 32) {
        __syncthreads();
        __builtin_amdgcn_global_load_lds(GLOBAL_AS(Ag + k0),
                                         LDS_AS(As + tid * 8), 16, 0, 0);
        __builtin_amdgcn_global_load_lds(GLOBAL_AS(Ag + (size_t)64 * K + k0),
                                         LDS_AS(As + 2048 + tid * 8), 16, 0, 0);
        __builtin_amdgcn_global_load_lds(GLOBAL_AS(Wg + k0),
                                         LDS_AS(Ws + tid * 8), 16, 0, 0);
        __builtin_amdgcn_global_load_lds(GLOBAL_AS(Wg + (size_t)64 * K + k0),
                                         LDS_AS(Ws + 2048 + tid * 8), 16, 0, 0);
        __syncthreads();

        bf16x8 af[4], wf[4];
        #pragma unroll
        for (int i = 0; i < 4; i++)
            af[i] = *(const bf16x8*)(As + (wr * 64 + i * 16 + l16) * 32 + quad * 8);
        #pragma unroll
        for (int j = 0; j < 4; j++)
            wf[j] = *(const bf16x8*)(Ws + (wc * 64 + j * 16 + l16) * 32 + quad * 8);
        #pragma unroll
        for (int i = 0; i < 4; i++)
            #pragma unroll
            for (int j = 0; j < 4; j++)
                acc[i][j] = __builtin_amdgcn_mfma_f32_16x16x32_bf16(
                    af[i], wf[j], acc[i][j], 0, 0, 0);
    }

    #pragma unroll
    for (int i = 0; i < 4; i++) {
        #pragma unroll
        for (int r = 0; r < 4; r++) {
            int row = bm * 128 + wr * 64 + i * 16 + quad * 4 + r;
            #pragma unroll
            for (int j = 0; j < 4; j++) {
                int col = bn * 128 + wc * 64 + j * 16 + l16;
                size_t idx = (size_t)row * N + col;
                C[idx] = acc[i][j][r] + resid[idx];
            }
        }
    }
}

// ---------------------------------------------------------------------------
// x_dbl = xs(bf16) @ x_proj^T(bf16, 64x768 zero-padded), f32 out (BLx64).
// ---------------------------------------------------------------------------
__global__ __launch_bounds__(256) void xdbl_mfma(
    const ushort_t* __restrict__ A, const ushort_t* __restrict__ W,
    float* __restrict__ C)
{
    __shared__ __bf16 As[128 * 32];
    __shared__ __bf16 Ws[64 * 32];
    int tid  = threadIdx.x;
    int bm = blockIdx.x;
    int lane = tid & 63, wave = tid >> 6;
    int quad = lane >> 4, l16 = lane & 15;

    const ushort_t* Ag = A + (size_t)(bm * 128 + (tid >> 2)) * D_INNER + (tid & 3) * 8;
    const ushort_t* Wg = W + (size_t)(tid >> 2) * D_INNER + (tid & 3) * 8;

    f32x4 acc[2][4] = {};

    for (int k0 = 0; k0 < D_INNER; k0 += 32) {
        __syncthreads();
        __builtin_amdgcn_global_load_lds(GLOBAL_AS(Ag + k0),
                                         LDS_AS(As + tid * 8), 16, 0, 0);
        __builtin_amdgcn_global_load_lds(GLOBAL_AS(Ag + (size_t)64 * D_INNER + k0),
                                         LDS_AS(As + 2048 + tid * 8), 16, 0, 0);
        __builtin_amdgcn_global_load_lds(GLOBAL_AS(Wg + k0),
                                         LDS_AS(Ws + tid * 8), 16, 0, 0);
        __syncthreads();

        bf16x8 af[2], wf[4];
        #pragma unroll
        for (int i = 0; i < 2; i++)
            af[i] = *(const bf16x8*)(As + (wave * 32 + i * 16 + l16) * 32 + quad * 8);
        #pragma unroll
        for (int j = 0; j < 4; j++)
            wf[j] = *(const bf16x8*)(Ws + (j * 16 + l16) * 32 + quad * 8);
        #pragma unroll
        for (int i = 0; i < 2; i++)
            #pragma unroll
            for (int j = 0; j < 4; j++)
                acc[i][j] = __builtin_amdgcn_mfma_f32_16x16x32_bf16(
                    af[i], wf[j], acc[i][j], 0, 0, 0);
    }

    #pragma unroll
    for (int i = 0; i < 2; i++) {
        #pragma unroll
        for (int r = 0; r < 4; r++) {
            int row = bm * 128 + wave * 32 + i * 16 + quad * 4 + r;
            #pragma unroll
            for (int j = 0; j < 4; j++) {
                int col = j * 16 + l16;
                C[(size_t)row * XDBL_LD + col] = acc[i][j][r];
            }
        }
    }
}

// ---------------------------------------------------------------------------
// dt = softplus(xdbl[:,0:24] @ dwt + bias), bf16 out.
// ---------------------------------------------------------------------------
__global__ __launch_bounds__(256) void dt_kernel(
    const float* __restrict__ xdbl, const float* __restrict__ dwt,
    const float* __restrict__ dtbias, ushort_t* __restrict__ dtb)
{
    int g    = blockIdx.x % 3;
    int row0 = (blockIdx.x / 3) * 16;
    int tid  = threadIdx.x;
    int d    = g * 256 + tid;
    float w[DT_RANK];
    #pragma unroll
    for (int r = 0; r < DT_RANK; r++) w[r] = dwt[r * D_INNER + d];
    float bias = dtbias[d];
    __shared__ float xd[16][DT_RANK];
    if (tid < 16 * DT_RANK) {
        int rr = tid / DT_RANK, cc = tid % DT_RANK;
        xd[rr][cc] = xdbl[(size_t)(row0 + rr) * XDBL_LD + cc];
    }
    __syncthreads();
    #pragma unroll 4
    for (int i = 0; i < 16; i++) {
        float acc = bias;
        #pragma unroll
        for (int r = 0; r < DT_RANK; r++) acc = fmaf(xd[i][r], w[r], acc);
        float sp = acc > 20.f ? acc : __logf(1.f + __expf(acc));
        dtb[(size_t)(row0 + i) * D_INNER + d] = f32_to_bf16_rne(sp);
    }
}

// ---------------------------------------------------------------------------
// Causal depthwise conv (k=4) + bias + SiLU, bf16 in/out, 8 ch per thread.
// ---------------------------------------------------------------------------
__global__ __launch_bounds__(256) void conv_silu_kernel(
    const ushort_t* __restrict__ xz, const float* __restrict__ cwt,
    const float* __restrict__ cb, ushort_t* __restrict__ xsc, int dir)
{
    int idx8 = blockIdx.x * 256 + threadIdx.x;   // BL * 96
    int c8   = (idx8 % 96) * 8;
    int row  = idx8 / 96;
    int l    = row % SEQ;
    int b0   = row - l;

    float acc[8];
    float4 bv0 = *(const float4*)(cb + c8);
    float4 bv1 = *(const float4*)(cb + c8 + 4);
    acc[0] = bv0.x; acc[1] = bv0.y; acc[2] = bv0.z; acc[3] = bv0.w;
    acc[4] = bv1.x; acc[5] = bv1.y; acc[6] = bv1.z; acc[7] = bv1.w;

    #pragma unroll
    for (int k = 0; k < 4; k++) {
        int ls = dir ? (l + k) : (l - 3 + k);
        int wk = dir ? (3 - k) : k;
        bool ok = dir ? (ls < SEQ) : (ls >= 0);
        if (ok) {
            u16x8 v = *(const u16x8*)(xz + (size_t)(b0 + ls) * 1536 + c8);
            float4 w0 = *(const float4*)(cwt + wk * D_INNER + c8);
            float4 w1 = *(const float4*)(cwt + wk * D_INNER + c8 + 4);
            float wv[8] = {w0.x, w0.y, w0.z, w0.w, w1.x, w1.y, w1.z, w1.w};
            #pragma unroll
            for (int j = 0; j < 8; j++)
                acc[j] = fmaf(bf16_to_f32(v[j]), wv[j], acc[j]);
        }
    }
    u16x8 o;
    #pragma unroll
    for (int j = 0; j < 8; j++) {
        float sg = 1.0f / (1.0f + __expf(-acc[j]));
        o[j] = f32_to_bf16_rne(acc[j] * sg);
    }
    *(u16x8*)(xsc + (size_t)row * D_INNER + c8) = o;
}

// ---------------------------------------------------------------------------
// Chunked selective scan, pass 1: per-chunk local scan from h=0.
// Fast path (flag): decay[n] = w^(n+1), w = exp2(-dt*log2e) -> 1 exp/step.
// hstate stored bf16.
// ---------------------------------------------------------------------------
__global__ __launch_bounds__(256) void scan_pass1(
    const ushort_t* __restrict__ xsc, const ushort_t* __restrict__ dtb,
    const float* __restrict__ xdbl, const float* __restrict__ alt,
    const int* __restrict__ flag,
    ushort_t* __restrict__ hstate, float* __restrict__ sumdt_buf, int dir)
{
    int g = blockIdx.x % 3;
    int c = (blockIdx.x / 3) % NCHUNK;
    int b = blockIdx.x / (3 * NCHUNK);
    int d = g * 256 + threadIdx.x;
    float h[D_STATE] = {};
    float sdt = 0.f;
    size_t base = (size_t)b * SEQ;

    if (flag[0]) {
        for (int i = 0; i < LCHUNK; i++) {
            int p = c * LCHUNK + i;
            int l = dir ? (SEQ - 1 - p) : p;
            size_t row = base + l;
            float dtv = bf16_to_f32(dtb[row * D_INNER + d]);
            float xv  = bf16_to_f32(xsc[row * D_INNER + d]);
            float dtx = dtv * xv;
            sdt += dtv;
            const float* Br = xdbl + row * XDBL_LD + DT_RANK;
            float w = __builtin_amdgcn_exp2f(-dtv * LOG2E);
            float pw = 1.f;
            #pragma unroll
            for (int n = 0; n < D_STATE; n++) {
                pw *= w;
                h[n] = fmaf(pw, h[n], dtx * Br[n]);
            }
        }
    } else {
        float A2[D_STATE];
        #pragma unroll
        for (int n = 0; n < D_STATE; n++)
            A2[n] = -__expf(alt[n * D_INNER + d]) * LOG2E;
        for (int i = 0; i < LCHUNK; i++) {
            int p = c * LCHUNK + i;
            int l = dir ? (SEQ - 1 - p) : p;
            size_t row = base + l;
            float dtv = bf16_to_f32(dtb[row * D_INNER + d]);
            float xv  = bf16_to_f32(xsc[row * D_INNER + d]);
            float dtx = dtv * xv;
            sdt += dtv;
            const float* Br = xdbl + row * XDBL_LD + DT_RANK;
            #pragma unroll
            for (int n = 0; n < D_STATE; n++)
                h[n] = fmaf(__builtin_amdgcn_exp2f(dtv * A2[n]), h[n], dtx * Br[n]);
        }
    }
    size_t cidx = (size_t)(b * NCHUNK + c) * D_INNER + d;
    sumdt_buf[cidx] = sdt;
    #pragma unroll
    for (int n = 0; n < D_STATE; n++)
        hstate[cidx * D_STATE + n] = f32_to_bf16_rne(h[n]);
}

// ---------------------------------------------------------------------------
// Pass 2: in-place combine (running carry in f32 registers); hstate[c]
// becomes the ENTRY state of chunk c (bf16 in memory).
// ---------------------------------------------------------------------------
__global__ __launch_bounds__(256) void scan_pass2(
    ushort_t* __restrict__ hstate, const float* __restrict__ sumdt_buf,
    const float* __restrict__ alt)
{
    int gid = blockIdx.x * 256 + threadIdx.x;   // BATCH * D_INNER * 16
    int n = gid & 15;
    int d = (gid >> 4) % D_INNER;
    int b = gid / (16 * D_INNER);
    float A2 = -__expf(alt[n * D_INNER + d]) * LOG2E;
    float h = 0.f;
    for (int c = 0; c < NCHUNK; c++) {
        size_t cidx = (size_t)(b * NCHUNK + c) * D_INNER + d;
        float ho = bf16_to_f32(hstate[cidx * D_STATE + n]);
        hstate[cidx * D_STATE + n] = f32_to_bf16_rne(h);
        h = fmaf(__builtin_amdgcn_exp2f(A2 * sumdt_buf[cidx]), h, ho);
    }
}

// ---------------------------------------------------------------------------
// Pass 3: local scan seeded with entry state; fast-path decay powers;
// fuses y = h.C + D*x and SiLU(z) gating; emits y bf16.
// ---------------------------------------------------------------------------
__global__ __launch_bounds__(256) void scan_pass3(
    const ushort_t* __restrict__ xsc, const ushort_t* __restrict__ dtb,
    const ushort_t* __restrict__ xz, const float* __restrict__ xdbl,
    const float* __restrict__ alt, const float* __restrict__ Dp,
    const int* __restrict__ flag, const ushort_t* __restrict__ hstate,
    ushort_t* __restrict__ y, int dir)
{
    int g = blockIdx.x % 3;
    int c = (blockIdx.x / 3) % NCHUNK;
    int b = blockIdx.x / (3 * NCHUNK);
    int d = g * 256 + threadIdx.x;
    size_t cidx = (size_t)(b * NCHUNK + c) * D_INNER + d;
    float h[D_STATE];
    #pragma unroll
    for (int n = 0; n < D_STATE; n++)
        h[n] = bf16_to_f32(hstate[cidx * D_STATE + n]);
    float Dd = Dp[d];
    size_t base = (size_t)b * SEQ;

    if (flag[0]) {
        for (int i = 0; i < LCHUNK; i++) {
            int p = c * LCHUNK + i;
            int l = dir ? (SEQ - 1 - p) : p;
            size_t row = base + l;
            float dtv = bf16_to_f32(dtb[row * D_INNER + d]);
            float xv  = bf16_to_f32(xsc[row * D_INNER + d]);
            float zv  = bf16_to_f32(xz[row * 1536 + D_INNER + d]);
            float dtx = dtv * xv;
            const float* Br = xdbl + row * XDBL_LD + DT_RANK;
            const float* Cr = Br + D_STATE;
            float w = __builtin_amdgcn_exp2f(-dtv * LOG2E);
            float pw = 1.f, yv = 0.f;
            #pragma unroll
            for (int n = 0; n < D_STATE; n++) {
                pw *= w;
                h[n] = fmaf(pw, h[n], dtx * Br[n]);
                yv = fmaf(h[n], Cr[n], yv);
            }
            yv = fmaf(xv, Dd, yv);
            float sg = 1.f / (1.f + __expf(-zv));
            yv *= zv * sg;
            y[row * D_INNER + d] = f32_to_bf16_rne(yv);
        }
    } else {
        float A2[D_STATE];
        #pragma unroll
        for (int n = 0; n < D_STATE; n++)
            A2[n] = -__expf(alt[n * D_INNER + d]) * LOG2E;
        for (int i = 0; i < LCHUNK; i++) {
            int p = c * LCHUNK + i;
            int l = dir ? (SEQ - 1 - p) : p;
            size_t row = base + l;
            float dtv = bf16_to_f32(dtb[row * D_INNER + d]);
            float xv  = bf16_to_f32(xsc[row * D_INNER + d]);
            float zv  = bf16_to_f32(xz[row * 1536 + D_INNER + d]);
            float dtx = dtv * xv;
            const float* Br = xdbl + row * XDBL_LD + DT_RANK;
            const float* Cr = Br + D_STATE;
            float yv = 0.f;
            #pragma unroll
            for (int n = 0; n < D_STATE; n++) {
                h[n] = fmaf(__builtin_amdgcn_exp2f(dtv * A2[n]), h[n], dtx * Br[n]);
                yv = fmaf(h[n], Cr[n], yv);
            }
            yv = fmaf(xv, Dd, yv);
            float sg = 1.f / (1.f + __expf(-zv));
            yv *= zv * sg;
            y[row * D_INNER + d] = f32_to_bf16_rne(yv);
        }
    }
}

// ---------------------------------------------------------------------------
extern "C" void kernel_launch(void* const* d_in, const int* in_sizes, int n_in,
                              void* d_out, int out_size, void* d_ws, size_t ws_size,
                              hipStream_t stream)
{
    const float* x       = (const float*)d_in[0];
    const float* norm_w  = (const float*)d_in[1];
    const float* norm_b  = (const float*)d_in[2];
    const float* in_proj = (const float*)d_in[3];
    const float* conv_w  = (const float*)d_in[4];
    const float* conv_b  = (const float*)d_in[5];
    const float* x_proj  = (const float*)d_in[6];
    const float* dt_w    = (const float*)d_in[7];
    const float* dt_b    = (const float*)d_in[8];
    const float* A_log   = (const float*)d_in[9];
    const float* Dp      = (const float*)d_in[10];
    const float* out_proj= (const float*)d_in[11];
    float* out = (float*)d_out;

    float* ws   = (float*)d_ws;
    // lnb (bf16 BL*384) and ybf (bf16 BL*768) share one region.
    float* reg0 = ws;                ws += (size_t)BL * D_INNER / 2;
    ushort_t* lnb = (ushort_t*)reg0;
    ushort_t* ybf = (ushort_t*)reg0;
    ushort_t* xzb  = (ushort_t*)ws;  ws += (size_t)BL * 1536 / 2;
    ushort_t* xscb = (ushort_t*)ws;  ws += (size_t)BL * D_INNER / 2;
    ushort_t* dtb  = (ushort_t*)ws;  ws += (size_t)BL * D_INNER / 2;
    float* xdbl = ws;                ws += (size_t)BL * XDBL_LD;
    float* sumdt  = ws;              ws += (size_t)BATCH * NCHUNK * D_INNER;
    ushort_t* hstate = (ushort_t*)ws; ws += (size_t)BATCH * NCHUNK * D_INNER * D_STATE / 2;
    ushort_t* wbf_in  = (ushort_t*)ws;  ws += (size_t)2 * 1536 * D_MODEL / 2;
    ushort_t* wbf_out = (ushort_t*)ws;  ws += (size_t)2 * D_MODEL * D_INNER / 2;
    ushort_t* xp_bf   = (ushort_t*)ws;  ws += (size_t)2 * 64 * D_INNER / 2;
    float* cwt = ws;                 ws += (size_t)2 * K_CONV * D_INNER;
    float* alt = ws;                 ws += (size_t)2 * D_STATE * D_INNER;
    float* dwt = ws;                 ws += (size_t)2 * DT_RANK * D_INNER;
    int* aflags = (int*)ws;          ws += 2;

    // one-shot weight prep (casts + transposes + A-structure check)
    cast_bf16_kernel<<<(2 * 1536 * D_MODEL + 255) / 256, 256, 0, stream>>>(
        in_proj, wbf_in, 2 * 1536 * D_MODEL);
    cast_bf16_kernel<<<(2 * D_MODEL * D_INNER + 255) / 256, 256, 0, stream>>>(
        out_proj, wbf_out, 2 * D_MODEL * D_INNER);
    cast_xproj_kernel<<<(2 * 64 * D_INNER + 255) / 256, 256, 0, stream>>>(
        x_proj, xp_bf);
    {
        int total = 2 * (K_CONV + D_STATE + DT_RANK) * D_INNER;
        prep_transpose_kernel<<<(total + 255) / 256, 256, 0, stream>>>(
            conv_w, A_log, dt_w, cwt, alt, dwt);
    }
    check_A_kernel<<<1, 256, 0, stream>>>(A_log, aflags);

    for (int i = 0; i < 2; i++) {
        const float* hinp = (i == 0) ? x : out;
        ln_kernel<<<BL, 384, 0, stream>>>(hinp, norm_w + i * D_MODEL,
                                          norm_b + i * D_MODEL, lnb);
        gemm_mfma_b16<<<dim3(BL / 128, 1536 / 128), 256, 0, stream>>>(
            lnb, wbf_in + (size_t)i * 1536 * D_MODEL, xzb, 1536, D_MODEL);
        conv_silu_kernel<<<(BL * 96) / 256, 256, 0, stream>>>(
            xzb, cwt + (size_t)i * K_CONV * D_INNER, conv_b + i * D_INNER,
            xscb, i);
        xdbl_mfma<<<BL / 128, 256, 0, stream>>>(
            xscb, xp_bf + (size_t)i * 64 * D_INNER, xdbl);
        dt_kernel<<<(BL / 16) * 3, 256, 0, stream>>>(
            xdbl, dwt + (size_t)i * DT_RANK * D_INNER, dt_b + i * D_INNER, dtb);
        scan_pass1<<<BATCH * NCHUNK * 3, 256, 0, stream>>>(
            xscb, dtb, xdbl, alt + (size_t)i * D_STATE * D_INNER,
            aflags + i, hstate, sumdt, i);
        scan_pass2<<<(BATCH * D_INNER * D_STATE) / 256, 256, 0, stream>>>(
            hstate, sumdt, alt + (size_t)i * D_STATE * D_INNER);
        scan_pass3<<<BATCH * NCHUNK * 3, 256, 0, stream>>>(
            xscb, dtb, xzb, xdbl, alt + (size_t)i * D_STATE * D_INNER,
            Dp + i * D_INNER, aflags + i, hstate, ybf, i);
        gemm_mfma_f32<<<dim3(BL / 128, D_MODEL / 128), 256, 0, stream>>>(
            ybf, wbf_out + (size_t)i * D_MODEL * D_INNER, hinp, out,
            D_MODEL, D_INNER);
    }
}